// Round 1
// baseline (2911.921 us; speedup 1.0000x reference)
//
#include <hip/hip_runtime.h>
#include <stdint.h>
#include <stddef.h>

#define FINF __builtin_inff()

// =================== Threefry-2x32 (JAX-compatible) ===================
__device__ inline void tf2x32(uint32_t k0, uint32_t k1, uint32_t x0, uint32_t x1,
                              uint32_t* o0, uint32_t* o1) {
  uint32_t ks2 = k0 ^ k1 ^ 0x1BD11BDAu;
  uint32_t v0 = x0 + k0, v1 = x1 + k1;
#define TFR(r) { v0 += v1; v1 = (v1 << (r)) | (v1 >> (32 - (r))); v1 ^= v0; }
  TFR(13) TFR(15) TFR(26) TFR(6)
  v0 += k1;  v1 += ks2 + 1u;
  TFR(17) TFR(29) TFR(16) TFR(24)
  v0 += ks2; v1 += k0 + 2u;
  TFR(13) TFR(15) TFR(26) TFR(6)
  v0 += k0;  v1 += k1 + 3u;
  TFR(17) TFR(29) TFR(16) TFR(24)
  v0 += k1;  v1 += ks2 + 4u;
  TFR(13) TFR(15) TFR(26) TFR(6)
  v0 += ks2; v1 += k0 + 5u;
#undef TFR
  *o0 = v0; *o1 = v1;
}

// jax.random.permutation(key(seed), n)[:m]  -- sort-based shuffle, stable.
// part=1: threefry_partitionable=True semantics (modern JAX default);
// part=0: legacy semantics (fallback if needed).
__global__ __launch_bounds__(1024) void perm_kernel(uint32_t seed, int n, int rounds,
                                                    int m, int* out, int part) {
  __shared__ unsigned long long keys[4096];
  __shared__ int vals[4096];
  __shared__ uint32_t kst[2];
  __shared__ uint32_t sk[2];
  int t = threadIdx.x;
  for (int i = t; i < n; i += 1024) vals[i] = i;
  if (t == 0) { kst[0] = 0u; kst[1] = seed; }
  __syncthreads();
  for (int r = 0; r < rounds; r++) {
    if (t == 0) {
      if (part) {
        uint32_t a0, a1, b0, b1;
        tf2x32(kst[0], kst[1], 0u, 0u, &a0, &a1);  // new key
        tf2x32(kst[0], kst[1], 0u, 1u, &b0, &b1);  // subkey
        kst[0] = a0; kst[1] = a1; sk[0] = b0; sk[1] = b1;
      } else {
        uint32_t p0, p1, q0, q1;
        tf2x32(kst[0], kst[1], 0u, 2u, &p0, &p1);  // pair (0,2)
        tf2x32(kst[0], kst[1], 1u, 3u, &q0, &q1);  // pair (1,3)
        kst[0] = p0; kst[1] = q0; sk[0] = p1; sk[1] = q1;
      }
    }
    __syncthreads();
    uint32_t s0 = sk[0], s1 = sk[1];
    if (part) {
      for (int i = t; i < n; i += 1024) {
        uint32_t y0, y1; tf2x32(s0, s1, 0u, (uint32_t)i, &y0, &y1);
        keys[i] = ((unsigned long long)(y0 ^ y1) << 32) | (unsigned)i;
      }
    } else {
      int half = n >> 1;
      for (int i = t; i < half; i += 1024) {
        uint32_t y0, y1; tf2x32(s0, s1, (uint32_t)i, (uint32_t)(i + half), &y0, &y1);
        keys[i]        = ((unsigned long long)y0 << 32) | (unsigned)i;
        keys[i + half] = ((unsigned long long)y1 << 32) | (unsigned)(i + half);
      }
    }
    __syncthreads();
    // bitonic sort ascending on 64-bit key (bits<<32 | pos) => stable sort by bits
    for (int kk = 2; kk <= n; kk <<= 1) {
      for (int j = kk >> 1; j > 0; j >>= 1) {
        for (int i = t; i < n; i += 1024) {
          int l = i ^ j;
          if (l > i) {
            unsigned long long ki = keys[i], kl = keys[l];
            bool up = ((i & kk) == 0);
            if (up ? (ki > kl) : (ki < kl)) {
              keys[i] = kl; keys[l] = ki;
              int v = vals[i]; vals[i] = vals[l]; vals[l] = v;
            }
          }
        }
        __syncthreads();
      }
    }
  }
  for (int i = t; i < m; i += 1024) out[i] = vals[i];
}

// =================== KNN: top-21 smallest dist, drop first ===================
// Replicates jax.lax.top_k(-dist, 21) tie-break: (dist asc, index asc).
template <int CNT>
__global__ void knn_kernel(const float* __restrict__ verts, int N,
                           int* __restrict__ idx20, int* __restrict__ idx4) {
  int row = blockIdx.x; int b = row / N, i = row - b * N;
  int t = threadIdx.x;
  const float* vb = verts + (size_t)b * N * 3;
  float xi = vb[i * 3], yi = vb[i * 3 + 1], zi = vb[i * 3 + 2];
  float sqi = (xi * xi + yi * yi) + zi * zi;
  float d[CNT];
#pragma unroll
  for (int m = 0; m < CNT; m++) {
    int j = (m << 8) + t;
    float xj = vb[j * 3], yj = vb[j * 3 + 1], zj = vb[j * 3 + 2];
    float sqj = (xj * xj + yj * yj) + zj * zj;
    float dot = (xi * xj + yi * yj) + zi * zj;
    d[m] = sqi + sqj - 2.f * dot;
  }
  __shared__ float sm[4]; __shared__ int si[4]; __shared__ int swin;
  for (int r = 0; r < 21; r++) {
    float best = FINF; int bj = 0x7fffffff;
#pragma unroll
    for (int m = 0; m < CNT; m++) {
      int j = (m << 8) + t;
      float dm = d[m];
      if (dm < best || (dm == best && j < bj)) { best = dm; bj = j; }
    }
    for (int off = 32; off; off >>= 1) {
      float ob = __shfl_down(best, off); int oj = __shfl_down(bj, off);
      if (ob < best || (ob == best && oj < bj)) { best = ob; bj = oj; }
    }
    if ((t & 63) == 0) { sm[t >> 6] = best; si[t >> 6] = bj; }
    __syncthreads();
    if (t == 0) {
      for (int w = 1; w < 4; w++)
        if (sm[w] < best || (sm[w] == best && si[w] < bj)) { best = sm[w]; bj = si[w]; }
      swin = bj;
      if (r >= 1) idx20[(size_t)row * 20 + (r - 1)] = bj;
      if (r >= 1 && r <= 4) idx4[(size_t)row * 4 + (r - 1)] = bj;
    }
    __syncthreads();
    int win = swin;
    int wm = win >> 8;
#pragma unroll
    for (int m = 0; m < CNT; m++)
      if (m == wm && (win & 255) == t) d[m] = FINF;
    __syncthreads();
  }
}

// =================== conv_surface + LN + relu -> fm0 (C=32) ===================
__global__ void conv_surface_kernel(const float* __restrict__ verts,
                                    const int* __restrict__ idx20,
                                    const float* __restrict__ d0,
                                    const float* __restrict__ g, const float* __restrict__ be,
                                    float* __restrict__ out, int N) {
  int row = blockIdx.x; int b = row / N, i = row - b * N;
  int t = threadIdx.x;
  __shared__ float nd[20][3];
  const float* vb = verts + (size_t)b * N * 3;
  if (t < 20) {
    int j = idx20[(size_t)row * 20 + t];
    float dx = vb[j * 3] - vb[i * 3], dy = vb[j * 3 + 1] - vb[i * 3 + 1], dz = vb[j * 3 + 2] - vb[i * 3 + 2];
    float n2 = sqrtf(dx * dx + dy * dy + dz * dz); n2 = fmaxf(n2, 1e-12f);
    nd[t][0] = dx / n2; nd[t][1] = dy / n2; nd[t][2] = dz / n2;
  }
  __syncthreads();
  float x = 0.f;
  if (t < 32) {
    float a = d0[t], bb2 = d0[32 + t], c = d0[64 + t];
    float nrm = fmaxf(sqrtf(a * a + bb2 * bb2 + c * c), 1e-12f);
    a /= nrm; bb2 /= nrm; c /= nrm;
    float mx = -FINF;
    for (int kk = 0; kk < 20; kk++) {
      float th = fmaxf(nd[kk][0] * a + nd[kk][1] * bb2 + nd[kk][2] * c, 0.f);
      mx = fmaxf(mx, th);
    }
    x = mx;
  }
  float s = x;
  for (int off = 32; off; off >>= 1) s += __shfl_xor(s, off);
  float mean = s / 32.f;
  float dev = (t < 32) ? x - mean : 0.f;
  float s2 = dev * dev;
  for (int off = 32; off; off >>= 1) s2 += __shfl_xor(s2, off);
  float var = s2 / 32.f;
  if (t < 32) {
    float y = (x - mean) / sqrtf(var + 1e-6f) * g[t] + be[t];
    out[(size_t)row * 32 + t] = fmaxf(y, 0.f);
  }
}

// =================== GEMM: y = x(R,I) @ W(I,O) + bias ===================
__global__ void gemm_io_kernel(const float* __restrict__ x, const float* __restrict__ W,
                               const float* __restrict__ bias, float* __restrict__ y,
                               int R, int I, int O) {
  int rb = blockIdx.x * 8;
  int o = blockIdx.y * blockDim.x + threadIdx.x;
  __shared__ float xs[8][256];
  for (int u = 0; u < 8; u++)
    for (int i2 = threadIdx.x; i2 < I; i2 += blockDim.x) xs[u][i2] = x[(size_t)(rb + u) * I + i2];
  __syncthreads();
  float a[8] = {0, 0, 0, 0, 0, 0, 0, 0};
  for (int k2 = 0; k2 < I; k2++) {
    float wv = W[(size_t)k2 * O + o];
#pragma unroll
    for (int u = 0; u < 8; u++) a[u] += xs[u][k2] * wv;
  }
  float bv = bias[o];
#pragma unroll
  for (int u = 0; u < 8; u++) y[(size_t)(rb + u) * O + o] = a[u] + bv;
}

// =================== conv_layer combine: center + max_k(theta*support), LN, relu ===================
template <int CPT>
__global__ void combine_kernel(const float* __restrict__ verts, const int* __restrict__ idx20,
                               const float* __restrict__ fo, const float* __restrict__ dirs,
                               const float* __restrict__ g, const float* __restrict__ be,
                               float* __restrict__ out, int N, int C) {
  int row = blockIdx.x; int b = row / N, i = row - b * N;
  int t = threadIdx.x, bs = blockDim.x;
  __shared__ float nd[20][3];
  __shared__ int nidx[20];
  __shared__ float red[8];
  const float* vb = verts + (size_t)b * N * 3;
  if (t < 20) {
    int j = idx20[(size_t)row * 20 + t];
    nidx[t] = j;
    float dx = vb[j * 3] - vb[i * 3], dy = vb[j * 3 + 1] - vb[i * 3 + 1], dz = vb[j * 3 + 2] - vb[i * 3 + 2];
    float n2 = fmaxf(sqrtf(dx * dx + dy * dy + dz * dz), 1e-12f);
    nd[t][0] = dx / n2; nd[t][1] = dy / n2; nd[t][2] = dz / n2;
  }
  __syncthreads();
  const float* fob = fo + (size_t)b * N * 2 * C;
  const float* forow = fob + (size_t)i * 2 * C;
  float xv[CPT];
  float ssum = 0.f;
#pragma unroll
  for (int u = 0; u < CPT; u++) {
    int c = t + u * bs;
    float da = dirs[c], db = dirs[C + c], dc = dirs[2 * C + c];
    float nrm = fmaxf(sqrtf(da * da + db * db + dc * dc), 1e-12f);
    da /= nrm; db /= nrm; dc /= nrm;
    float mx = -FINF;
    for (int kk = 0; kk < 20; kk++) {
      float th = fmaxf(nd[kk][0] * da + nd[kk][1] * db + nd[kk][2] * dc, 0.f);
      float sup = fob[(size_t)nidx[kk] * 2 * C + C + c];
      mx = fmaxf(mx, th * sup);
    }
    float val = forow[c] + mx;
    xv[u] = val; ssum += val;
  }
  int nw = bs >> 6;
  for (int off = 32; off; off >>= 1) ssum += __shfl_down(ssum, off);
  if ((t & 63) == 0) red[t >> 6] = ssum;
  __syncthreads();
  if (t == 0) { float s = red[0]; for (int w = 1; w < nw; w++) s += red[w]; red[0] = s; }
  __syncthreads();
  float mean = red[0] / (float)C;
  __syncthreads();
  float s2 = 0.f;
#pragma unroll
  for (int u = 0; u < CPT; u++) { float d2 = xv[u] - mean; s2 += d2 * d2; }
  for (int off = 32; off; off >>= 1) s2 += __shfl_down(s2, off);
  if ((t & 63) == 0) red[t >> 6] = s2;
  __syncthreads();
  if (t == 0) { float s = red[0]; for (int w = 1; w < nw; w++) s += red[w]; red[0] = s; }
  __syncthreads();
  float inv = 1.0f / sqrtf(red[0] / (float)C + 1e-6f);
#pragma unroll
  for (int u = 0; u < CPT; u++) {
    int c = t + u * bs;
    float yv = (xv[u] - mean) * inv * g[c] + be[c];
    out[(size_t)row * C + c] = fmaxf(yv, 0.f);
  }
}

// =================== pool (max over 4 NN) + row-select ===================
__global__ void pool_select_kernel(const float* __restrict__ fm, const int* __restrict__ idx4,
                                   const int* __restrict__ sel, const float* __restrict__ vin,
                                   float* __restrict__ vout, float* __restrict__ out,
                                   int N, int M, int C) {
  int row = blockIdx.x; int b = row / M, r = row - b * M;
  int s = sel[r];
  const int* id = idx4 + ((size_t)b * N + s) * 4;
  int i0 = id[0], i1 = id[1], i2 = id[2], i3 = id[3];
  const float* fb = fm + (size_t)b * N * C;
  for (int c = threadIdx.x; c < C; c += blockDim.x) {
    float m = fmaxf(fmaxf(fb[(size_t)i0 * C + c], fb[(size_t)i1 * C + c]),
                    fmaxf(fb[(size_t)i2 * C + c], fb[(size_t)i3 * C + c]));
    out[((size_t)b * M + r) * C + c] = m;
  }
  if (vout != nullptr && threadIdx.x < 3)
    vout[((size_t)b * M + r) * 3 + threadIdx.x] = vin[((size_t)b * N + s) * 3 + threadIdx.x];
}

// =================== token transpose: tok[b,n,e] = token[e*1024+n] ===================
__global__ void tok_kernel(const float* __restrict__ token, float* __restrict__ tok) {
  int id = blockIdx.x * 256 + threadIdx.x;  // 4*1024*64
  int e = id & 63; int n = (id >> 6) & 1023;
  tok[id] = token[e * 1024 + n];
}

// =================== linear: y = x(R,I) @ W(O,I)^T + bias (+res) ===================
__global__ void linear_oi_kernel(const float* __restrict__ x, const float* __restrict__ W,
                                 const float* __restrict__ bias, const float* __restrict__ res,
                                 float* __restrict__ y, int R, int I, int O) {
  int rb = blockIdx.x * 8;
  int o = threadIdx.x;  // blockDim.x == O
  __shared__ float xs[8][256];
  for (int u = 0; u < 8; u++)
    for (int i2 = threadIdx.x; i2 < I; i2 += O) xs[u][i2] = x[(size_t)(rb + u) * I + i2];
  __syncthreads();
  float a[8] = {0, 0, 0, 0, 0, 0, 0, 0};
  const float* w = W + (size_t)o * I;
  for (int k2 = 0; k2 < I; k2++) {
    float wv = w[k2];
#pragma unroll
    for (int u = 0; u < 8; u++) a[u] += xs[u][k2] * wv;
  }
  float bv = bias[o];
#pragma unroll
  for (int u = 0; u < 8; u++) {
    float val = a[u] + bv;
    if (res) val += res[(size_t)(rb + u) * O + o];
    y[(size_t)(rb + u) * O + o] = val;
  }
}

// =================== attention (one block per b,h,q row) ===================
__global__ void attn_kernel(const float* __restrict__ q, const float* __restrict__ k,
                            const float* __restrict__ v, float* __restrict__ o,
                            int Lq, int Lk, int H, int HD, float scale) {
  __shared__ float p[1024];
  __shared__ float acc_s[256];
  __shared__ float red[4];
  int t = threadIdx.x;
  int id = blockIdx.x;
  int qn = id % Lq; int bh = id / Lq; int h = bh % H; int b = bh / H;
  int E = H * HD;
  const float* qrow = q + ((size_t)b * Lq + qn) * E + h * HD;
  const float* kb = k + (size_t)b * Lk * E + h * HD;
  const float* vb = v + (size_t)b * Lk * E + h * HD;
  float lmax = -FINF;
  for (int j = t; j < Lk; j += 256) {
    const float* kr = kb + (size_t)j * E;
    float s = 0.f;
    for (int d = 0; d < HD; d++) s += qrow[d] * kr[d];
    s *= scale; p[j] = s; lmax = fmaxf(lmax, s);
  }
  for (int off = 32; off; off >>= 1) lmax = fmaxf(lmax, __shfl_down(lmax, off));
  if ((t & 63) == 0) red[t >> 6] = lmax;
  __syncthreads();
  if (t == 0) { float m = red[0]; for (int i = 1; i < 4; i++) m = fmaxf(m, red[i]); red[0] = m; }
  __syncthreads();
  float gmax = red[0];
  __syncthreads();
  float lsum = 0.f;
  for (int j = t; j < Lk; j += 256) { float e = expf(p[j] - gmax); p[j] = e; lsum += e; }
  for (int off = 32; off; off >>= 1) lsum += __shfl_down(lsum, off);
  if ((t & 63) == 0) red[t >> 6] = lsum;
  __syncthreads();
  if (t == 0) { float s = red[0]; for (int i = 1; i < 4; i++) s += red[i]; red[0] = s; }
  __syncthreads();
  float inv = 1.0f / red[0];
  int d = t % HD; int chunk = t / HD; int nch = 256 / HD;
  float acc = 0.f;
  for (int j = chunk; j < Lk; j += nch) acc += p[j] * vb[(size_t)j * E + d];
  acc_s[t] = acc;
  __syncthreads();
  if (t < HD) {
    float s = acc_s[t];
    for (int c2 = 1; c2 < nch; c2++) s += acc_s[c2 * HD + t];
    o[((size_t)b * Lq + qn) * E + h * HD + t] = s * inv;
  }
}

// =================== BN (train-mode) stats & apply ===================
__global__ void bn_stats_kernel(const float* __restrict__ x, float* __restrict__ stats,
                                int R, int C) {
  int c = blockIdx.x; int t = threadIdx.x;
  __shared__ float red[8];
  float s = 0.f;
  for (int r = t; r < R; r += blockDim.x) s += x[(size_t)r * C + c];
  for (int off = 32; off; off >>= 1) s += __shfl_down(s, off);
  if ((t & 63) == 0) red[t >> 6] = s;
  __syncthreads();
  if (t == 0) { float a = red[0]; for (int w = 1; w < (int)(blockDim.x >> 6); w++) a += red[w]; red[0] = a; }
  __syncthreads();
  float mean = red[0] / (float)R;
  __syncthreads();
  float s2 = 0.f;
  for (int r = t; r < R; r += blockDim.x) { float d = x[(size_t)r * C + c] - mean; s2 += d * d; }
  for (int off = 32; off; off >>= 1) s2 += __shfl_down(s2, off);
  if ((t & 63) == 0) red[t >> 6] = s2;
  __syncthreads();
  if (t == 0) {
    float a = red[0]; for (int w = 1; w < (int)(blockDim.x >> 6); w++) a += red[w];
    stats[c] = mean; stats[C + c] = a / (float)R;
  }
}

__global__ void bn_apply_kernel(float* __restrict__ x, const float* __restrict__ stats,
                                const float* __restrict__ g, const float* __restrict__ b2,
                                int total, int C) {
  int id = blockIdx.x * blockDim.x + threadIdx.x;
  if (id >= total) return;
  int c = id % C;
  float y = (x[id] - stats[c]) / sqrtf(stats[C + c] + 1e-5f) * g[c] + b2[c];
  x[id] = fmaxf(y, 0.f);
}

// =================== final conv1x1: out[b,o,n] = fmf[b,n,:]·W[o,:] + bias ===================
__global__ void final_kernel(const float* __restrict__ fmf, const float* __restrict__ W,
                             const float* __restrict__ bias, float* __restrict__ out) {
  int nb = blockIdx.x * 8;  // global row r = b*1024 + n
  int o = threadIdx.x;      // 256
  __shared__ float xs[8][1024];
  for (int u = 0; u < 8; u++)
    for (int c = threadIdx.x; c < 1024; c += 256) xs[u][c] = fmf[(size_t)(nb + u) * 1024 + c];
  __syncthreads();
  float acc[8] = {0, 0, 0, 0, 0, 0, 0, 0};
  const float* w = W + (size_t)o * 1024;
  for (int c = 0; c < 1024; c++) {
    float wv = w[c];
#pragma unroll
    for (int u = 0; u < 8; u++) acc[u] += xs[u][c] * wv;
  }
  float bv = bias[o];
#pragma unroll
  for (int u = 0; u < 8; u++) {
    int r = nb + u; int b = r >> 10; int n = r & 1023;
    out[((size_t)(b * 256 + o) << 10) + n] = acc[u] + bv;
  }
}

// =================== launch ===================
extern "C" void kernel_launch(void* const* d_in, const int* in_sizes, int n_in,
                              void* d_out, int out_size, void* d_ws, size_t ws_size,
                              hipStream_t stream) {
  (void)in_sizes; (void)n_in; (void)out_size;
  const float* vertices = (const float*)d_in[0];
  const float* d0       = (const float*)d_in[1];
  const float* g0       = (const float*)d_in[2];
  const float* be0      = (const float*)d_in[3];
  const float* w1       = (const float*)d_in[4];
  const float* b1       = (const float*)d_in[5];
  const float* dir1     = (const float*)d_in[6];
  const float* g1       = (const float*)d_in[7];
  const float* be1      = (const float*)d_in[8];
  const float* w2       = (const float*)d_in[9];
  const float* b2       = (const float*)d_in[10];
  const float* dir2     = (const float*)d_in[11];
  const float* g2       = (const float*)d_in[12];
  const float* be2      = (const float*)d_in[13];
  const float* w3       = (const float*)d_in[14];
  const float* b3       = (const float*)d_in[15];
  const float* dir3     = (const float*)d_in[16];
  const float* g3       = (const float*)d_in[17];
  const float* be3      = (const float*)d_in[18];
  const float* token    = (const float*)d_in[19];
  const float* a1_in_w  = (const float*)d_in[20];
  const float* a1_in_b  = (const float*)d_in[21];
  const float* a1_out_w = (const float*)d_in[22];
  const float* a1_out_b = (const float*)d_in[23];
  const float* ffn1_w   = (const float*)d_in[24];
  const float* ffn1_b   = (const float*)d_in[25];
  const float* bg       = (const float*)d_in[26];
  const float* bbp      = (const float*)d_in[27];
  const float* ffn2_w   = (const float*)d_in[28];
  const float* ffn2_b   = (const float*)d_in[29];
  const float* a2_in_w  = (const float*)d_in[30];
  const float* a2_in_b  = (const float*)d_in[31];
  const float* a2_out_w = (const float*)d_in[32];
  const float* a2_out_b = (const float*)d_in[33];
  const float* w7       = (const float*)d_in[34];
  const float* b7       = (const float*)d_in[35];
  const float* dir7     = (const float*)d_in[36];
  const float* g4       = (const float*)d_in[37];
  const float* be4      = (const float*)d_in[38];
  const float* c8_w     = (const float*)d_in[39];
  const float* c8_b     = (const float*)d_in[40];
  float* out = (float*)d_out;
  float* ws = (float*)d_ws;

  if (ws_size < 78568448u) return;  // ~75 MB needed

  // slabs (float offsets); lifetimes verified non-overlapping
  float* FO     = ws + 0;           // 8388608: fo1/fo2/fo3/fo7
  float* S1     = ws + 8388608;     // 4194304: fm1 / attn2 / fmf
  float* S2     = ws + 12582912;    // 1048576: fm0 / fm2 / x1
  float* S3     = ws + 13631488;    // 1048576: fm3 / query / q2
  float* QUERY2 = ws + 14680064;    // 1048576
  float* CROSS  = ws + 15728640;    // 1048576
  float* FM1P   = ws + 16777216;    // 262144
  float* FM3P   = FM1P + 262144;
  float* TOK    = FM3P + 262144;
  float* Q1     = TOK + 262144;
  float* K1     = Q1 + 262144;
  float* VA1    = K1 + 262144;
  float* ATT1   = VA1 + 262144;
  float* K2     = ATT1 + 262144;
  float* V2     = K2 + 262144;
  float* V1     = V2 + 262144;      // 12288
  float* BNST   = V1 + 12288;       // 512
  int* IDX20_0  = (int*)(BNST + 512);      // 327680
  int* IDX4_0   = IDX20_0 + 327680;        // 65536
  int* IDX20_1  = IDX4_0 + 65536;          // 81920
  int* IDX4_1   = IDX20_1 + 81920;         // 16384
  int* SEL1     = IDX4_1 + 16384;          // 1024
  int* SEL2     = SEL1 + 1024;             // 256

  // PRNG permutations (partitionable threefry; flip last arg to 0 if mismatch)
  perm_kernel<<<1, 1024, 0, stream>>>(1u, 4096, 2, 1024, SEL1, 1);
  perm_kernel<<<1, 1024, 0, stream>>>(2u, 1024, 1, 256, SEL2, 1);

  // stage 0: knn on v0, conv_surface, conv_layer1
  knn_kernel<16><<<4 * 4096, 256, 0, stream>>>(vertices, 4096, IDX20_0, IDX4_0);
  conv_surface_kernel<<<4 * 4096, 64, 0, stream>>>(vertices, IDX20_0, d0, g0, be0, S2, 4096);
  gemm_io_kernel<<<dim3(2048, 1), 128, 0, stream>>>(S2, w1, b1, FO, 16384, 32, 128);
  combine_kernel<1><<<16384, 64, 0, stream>>>(vertices, IDX20_0, FO, dir1, g1, be1, S1, 4096, 64);
  pool_select_kernel<<<4096, 64, 0, stream>>>(S1, IDX4_0, SEL1, vertices, V1, FM1P, 4096, 1024, 64);

  // stage 1: knn on v1, conv_layer2/3, pool2
  knn_kernel<4><<<4 * 1024, 256, 0, stream>>>(V1, 1024, IDX20_1, IDX4_1);
  gemm_io_kernel<<<dim3(512, 1), 256, 0, stream>>>(FM1P, w2, b2, FO, 4096, 64, 256);
  combine_kernel<1><<<4096, 128, 0, stream>>>(V1, IDX20_1, FO, dir2, g2, be2, S2, 1024, 128);
  gemm_io_kernel<<<dim3(512, 2), 256, 0, stream>>>(S2, w3, b3, FO, 4096, 128, 512);
  combine_kernel<1><<<4096, 256, 0, stream>>>(V1, IDX20_1, FO, dir3, g3, be3, S3, 1024, 256);
  pool_select_kernel<<<1024, 256, 0, stream>>>(S3, IDX4_1, SEL2, nullptr, nullptr, FM3P, 1024, 256, 256);

  // MHA1 (tok as Q, fm1p as KV) + residual
  tok_kernel<<<1024, 256, 0, stream>>>(token, TOK);
  linear_oi_kernel<<<512, 64, 0, stream>>>(TOK, a1_in_w, a1_in_b, nullptr, Q1, 4096, 64, 64);
  linear_oi_kernel<<<512, 64, 0, stream>>>(FM1P, a1_in_w + 64 * 64, a1_in_b + 64, nullptr, K1, 4096, 64, 64);
  linear_oi_kernel<<<512, 64, 0, stream>>>(FM1P, a1_in_w + 128 * 64, a1_in_b + 128, nullptr, VA1, 4096, 64, 64);
  attn_kernel<<<16384, 256, 0, stream>>>(Q1, K1, VA1, ATT1, 1024, 1024, 4, 16, 0.25f);
  linear_oi_kernel<<<512, 64, 0, stream>>>(ATT1, a1_out_w, a1_out_b, FM1P, S3, 4096, 64, 64);  // query

  // FFN (conv1x1 -> BN -> relu -> conv1x1)
  linear_oi_kernel<<<512, 256, 0, stream>>>(S3, ffn1_w, ffn1_b, nullptr, S2, 4096, 64, 256);   // x1
  bn_stats_kernel<<<256, 256, 0, stream>>>(S2, BNST, 4096, 256);
  bn_apply_kernel<<<4096, 256, 0, stream>>>(S2, BNST, bg, bbp, 4096 * 256, 256);
  linear_oi_kernel<<<512, 256, 0, stream>>>(S2, ffn2_w, ffn2_b, nullptr, QUERY2, 4096, 256, 256);

  // MHA2 (query2 as Q, fm3p as KV) + residual
  linear_oi_kernel<<<512, 256, 0, stream>>>(QUERY2, a2_in_w, a2_in_b, nullptr, S3, 4096, 256, 256);          // q2
  linear_oi_kernel<<<128, 256, 0, stream>>>(FM3P, a2_in_w + 256 * 256, a2_in_b + 256, nullptr, K2, 1024, 256, 256);
  linear_oi_kernel<<<128, 256, 0, stream>>>(FM3P, a2_in_w + 512 * 256, a2_in_b + 512, nullptr, V2, 1024, 256, 256);
  attn_kernel<<<16384, 256, 0, stream>>>(S3, K2, V2, S1, 1024, 256, 4, 64, 0.125f);                          // attn2
  linear_oi_kernel<<<512, 256, 0, stream>>>(S1, a2_out_w, a2_out_b, QUERY2, CROSS, 4096, 256, 256);          // cross

  // conv_layer7 + final conv1x1
  gemm_io_kernel<<<dim3(512, 8), 256, 0, stream>>>(CROSS, w7, b7, FO, 4096, 256, 2048);
  combine_kernel<4><<<4096, 256, 0, stream>>>(V1, IDX20_1, FO, dir7, g4, be4, S1, 1024, 1024);               // fmf
  final_kernel<<<512, 256, 0, stream>>>(S1, c8_w, c8_b, out);
}

// Round 2
// 1493.403 us; speedup vs baseline: 1.9499x; 1.9499x over previous
//
#include <hip/hip_runtime.h>
#include <stdint.h>
#include <stddef.h>

#define FINF __builtin_inff()

// =================== Threefry-2x32 (JAX-compatible) ===================
__device__ inline void tf2x32(uint32_t k0, uint32_t k1, uint32_t x0, uint32_t x1,
                              uint32_t* o0, uint32_t* o1) {
  uint32_t ks2 = k0 ^ k1 ^ 0x1BD11BDAu;
  uint32_t v0 = x0 + k0, v1 = x1 + k1;
#define TFR(r) { v0 += v1; v1 = (v1 << (r)) | (v1 >> (32 - (r))); v1 ^= v0; }
  TFR(13) TFR(15) TFR(26) TFR(6)
  v0 += k1;  v1 += ks2 + 1u;
  TFR(17) TFR(29) TFR(16) TFR(24)
  v0 += ks2; v1 += k0 + 2u;
  TFR(13) TFR(15) TFR(26) TFR(6)
  v0 += k0;  v1 += k1 + 3u;
  TFR(17) TFR(29) TFR(16) TFR(24)
  v0 += k1;  v1 += ks2 + 4u;
  TFR(13) TFR(15) TFR(26) TFR(6)
  v0 += ks2; v1 += k0 + 5u;
#undef TFR
  *o0 = v0; *o1 = v1;
}

// jax.random.permutation(key(seed), n)[:m]  -- sort-based shuffle, stable.
__global__ __launch_bounds__(1024) void perm_kernel(uint32_t seed, int n, int rounds,
                                                    int m, int* out, int part) {
  __shared__ unsigned long long keys[4096];
  __shared__ int vals[4096];
  __shared__ uint32_t kst[2];
  __shared__ uint32_t sk[2];
  int t = threadIdx.x;
  for (int i = t; i < n; i += 1024) vals[i] = i;
  if (t == 0) { kst[0] = 0u; kst[1] = seed; }
  __syncthreads();
  for (int r = 0; r < rounds; r++) {
    if (t == 0) {
      if (part) {
        uint32_t a0, a1, b0, b1;
        tf2x32(kst[0], kst[1], 0u, 0u, &a0, &a1);  // new key
        tf2x32(kst[0], kst[1], 0u, 1u, &b0, &b1);  // subkey
        kst[0] = a0; kst[1] = a1; sk[0] = b0; sk[1] = b1;
      } else {
        uint32_t p0, p1, q0, q1;
        tf2x32(kst[0], kst[1], 0u, 2u, &p0, &p1);
        tf2x32(kst[0], kst[1], 1u, 3u, &q0, &q1);
        kst[0] = p0; kst[1] = q0; sk[0] = p1; sk[1] = q1;
      }
    }
    __syncthreads();
    uint32_t s0 = sk[0], s1 = sk[1];
    if (part) {
      for (int i = t; i < n; i += 1024) {
        uint32_t y0, y1; tf2x32(s0, s1, 0u, (uint32_t)i, &y0, &y1);
        keys[i] = ((unsigned long long)(y0 ^ y1) << 32) | (unsigned)i;
      }
    } else {
      int half = n >> 1;
      for (int i = t; i < half; i += 1024) {
        uint32_t y0, y1; tf2x32(s0, s1, (uint32_t)i, (uint32_t)(i + half), &y0, &y1);
        keys[i]        = ((unsigned long long)y0 << 32) | (unsigned)i;
        keys[i + half] = ((unsigned long long)y1 << 32) | (unsigned)(i + half);
      }
    }
    __syncthreads();
    for (int kk = 2; kk <= n; kk <<= 1) {
      for (int j = kk >> 1; j > 0; j >>= 1) {
        for (int i = t; i < n; i += 1024) {
          int l = i ^ j;
          if (l > i) {
            unsigned long long ki = keys[i], kl = keys[l];
            bool up = ((i & kk) == 0);
            if (up ? (ki > kl) : (ki < kl)) {
              keys[i] = kl; keys[l] = ki;
              int v = vals[i]; vals[i] = vals[l]; vals[l] = v;
            }
          }
        }
        __syncthreads();
      }
    }
  }
  for (int i = t; i < m; i += 1024) out[i] = vals[i];
}

// =================== KNN: top-21 smallest dist, drop first ===================
template <int CNT>
__global__ void knn_kernel(const float* __restrict__ verts, int N,
                           int* __restrict__ idx20, int* __restrict__ idx4) {
  int row = blockIdx.x; int b = row / N, i = row - b * N;
  int t = threadIdx.x;
  const float* vb = verts + (size_t)b * N * 3;
  float xi = vb[i * 3], yi = vb[i * 3 + 1], zi = vb[i * 3 + 2];
  float sqi = (xi * xi + yi * yi) + zi * zi;
  float d[CNT];
#pragma unroll
  for (int m = 0; m < CNT; m++) {
    int j = (m << 8) + t;
    float xj = vb[j * 3], yj = vb[j * 3 + 1], zj = vb[j * 3 + 2];
    float sqj = (xj * xj + yj * yj) + zj * zj;
    float dot = (xi * xj + yi * yj) + zi * zj;
    d[m] = sqi + sqj - 2.f * dot;
  }
  __shared__ float sm[4]; __shared__ int si[4]; __shared__ int swin;
  for (int r = 0; r < 21; r++) {
    float best = FINF; int bj = 0x7fffffff;
#pragma unroll
    for (int m = 0; m < CNT; m++) {
      int j = (m << 8) + t;
      float dm = d[m];
      if (dm < best || (dm == best && j < bj)) { best = dm; bj = j; }
    }
    for (int off = 32; off; off >>= 1) {
      float ob = __shfl_down(best, off); int oj = __shfl_down(bj, off);
      if (ob < best || (ob == best && oj < bj)) { best = ob; bj = oj; }
    }
    if ((t & 63) == 0) { sm[t >> 6] = best; si[t >> 6] = bj; }
    __syncthreads();
    if (t == 0) {
      for (int w = 1; w < 4; w++)
        if (sm[w] < best || (sm[w] == best && si[w] < bj)) { best = sm[w]; bj = si[w]; }
      swin = bj;
      if (r >= 1) idx20[(size_t)row * 20 + (r - 1)] = bj;
      if (r >= 1 && r <= 4) idx4[(size_t)row * 4 + (r - 1)] = bj;
    }
    __syncthreads();
    int win = swin;
    int wm = win >> 8;
#pragma unroll
    for (int m = 0; m < CNT; m++)
      if (m == wm && (win & 255) == t) d[m] = FINF;
    __syncthreads();
  }
}

// =================== conv_surface + LN + relu -> fm0 (C=32) ===================
__global__ void conv_surface_kernel(const float* __restrict__ verts,
                                    const int* __restrict__ idx20,
                                    const float* __restrict__ d0,
                                    const float* __restrict__ g, const float* __restrict__ be,
                                    float* __restrict__ out, int N) {
  int row = blockIdx.x; int b = row / N, i = row - b * N;
  int t = threadIdx.x;
  __shared__ float nd[20][3];
  const float* vb = verts + (size_t)b * N * 3;
  if (t < 20) {
    int j = idx20[(size_t)row * 20 + t];
    float dx = vb[j * 3] - vb[i * 3], dy = vb[j * 3 + 1] - vb[i * 3 + 1], dz = vb[j * 3 + 2] - vb[i * 3 + 2];
    float n2 = sqrtf(dx * dx + dy * dy + dz * dz); n2 = fmaxf(n2, 1e-12f);
    nd[t][0] = dx / n2; nd[t][1] = dy / n2; nd[t][2] = dz / n2;
  }
  __syncthreads();
  float x = 0.f;
  if (t < 32) {
    float a = d0[t], bb2 = d0[32 + t], c = d0[64 + t];
    float nrm = fmaxf(sqrtf(a * a + bb2 * bb2 + c * c), 1e-12f);
    a /= nrm; bb2 /= nrm; c /= nrm;
    float mx = -FINF;
    for (int kk = 0; kk < 20; kk++) {
      float th = fmaxf(nd[kk][0] * a + nd[kk][1] * bb2 + nd[kk][2] * c, 0.f);
      mx = fmaxf(mx, th);
    }
    x = mx;
  }
  float s = x;
  for (int off = 32; off; off >>= 1) s += __shfl_xor(s, off);
  float mean = s / 32.f;
  float dev = (t < 32) ? x - mean : 0.f;
  float s2 = dev * dev;
  for (int off = 32; off; off >>= 1) s2 += __shfl_xor(s2, off);
  float var = s2 / 32.f;
  if (t < 32) {
    float y = (x - mean) / sqrtf(var + 1e-6f) * g[t] + be[t];
    out[(size_t)row * 32 + t] = fmaxf(y, 0.f);
  }
}

// =================== GEMM: y = x(R,I) @ W(I,O) + bias ===================
__global__ void gemm_io_kernel(const float* __restrict__ x, const float* __restrict__ W,
                               const float* __restrict__ bias, float* __restrict__ y,
                               int R, int I, int O) {
  int rb = blockIdx.x * 8;
  int o = blockIdx.y * blockDim.x + threadIdx.x;
  __shared__ float xs[8][256];
  for (int u = 0; u < 8; u++)
    for (int i2 = threadIdx.x; i2 < I; i2 += blockDim.x) xs[u][i2] = x[(size_t)(rb + u) * I + i2];
  __syncthreads();
  float a[8] = {0, 0, 0, 0, 0, 0, 0, 0};
  for (int k2 = 0; k2 < I; k2++) {
    float wv = W[(size_t)k2 * O + o];
#pragma unroll
    for (int u = 0; u < 8; u++) a[u] += xs[u][k2] * wv;
  }
  float bv = bias[o];
#pragma unroll
  for (int u = 0; u < 8; u++) y[(size_t)(rb + u) * O + o] = a[u] + bv;
}

// =================== conv_layer combine ===================
template <int CPT>
__global__ void combine_kernel(const float* __restrict__ verts, const int* __restrict__ idx20,
                               const float* __restrict__ fo, const float* __restrict__ dirs,
                               const float* __restrict__ g, const float* __restrict__ be,
                               float* __restrict__ out, int N, int C) {
  int row = blockIdx.x; int b = row / N, i = row - b * N;
  int t = threadIdx.x, bs = blockDim.x;
  __shared__ float nd[20][3];
  __shared__ int nidx[20];
  __shared__ float red[8];
  const float* vb = verts + (size_t)b * N * 3;
  if (t < 20) {
    int j = idx20[(size_t)row * 20 + t];
    nidx[t] = j;
    float dx = vb[j * 3] - vb[i * 3], dy = vb[j * 3 + 1] - vb[i * 3 + 1], dz = vb[j * 3 + 2] - vb[i * 3 + 2];
    float n2 = fmaxf(sqrtf(dx * dx + dy * dy + dz * dz), 1e-12f);
    nd[t][0] = dx / n2; nd[t][1] = dy / n2; nd[t][2] = dz / n2;
  }
  __syncthreads();
  const float* fob = fo + (size_t)b * N * 2 * C;
  const float* forow = fob + (size_t)i * 2 * C;
  float xv[CPT];
  float ssum = 0.f;
#pragma unroll
  for (int u = 0; u < CPT; u++) {
    int c = t + u * bs;
    float da = dirs[c], db = dirs[C + c], dc = dirs[2 * C + c];
    float nrm = fmaxf(sqrtf(da * da + db * db + dc * dc), 1e-12f);
    da /= nrm; db /= nrm; dc /= nrm;
    float mx = -FINF;
    for (int kk = 0; kk < 20; kk++) {
      float th = fmaxf(nd[kk][0] * da + nd[kk][1] * db + nd[kk][2] * dc, 0.f);
      float sup = fob[(size_t)nidx[kk] * 2 * C + C + c];
      mx = fmaxf(mx, th * sup);
    }
    float val = forow[c] + mx;
    xv[u] = val; ssum += val;
  }
  int nw = bs >> 6;
  for (int off = 32; off; off >>= 1) ssum += __shfl_down(ssum, off);
  if ((t & 63) == 0) red[t >> 6] = ssum;
  __syncthreads();
  if (t == 0) { float s = red[0]; for (int w = 1; w < nw; w++) s += red[w]; red[0] = s; }
  __syncthreads();
  float mean = red[0] / (float)C;
  __syncthreads();
  float s2 = 0.f;
#pragma unroll
  for (int u = 0; u < CPT; u++) { float d2 = xv[u] - mean; s2 += d2 * d2; }
  for (int off = 32; off; off >>= 1) s2 += __shfl_down(s2, off);
  if ((t & 63) == 0) red[t >> 6] = s2;
  __syncthreads();
  if (t == 0) { float s = red[0]; for (int w = 1; w < nw; w++) s += red[w]; red[0] = s; }
  __syncthreads();
  float inv = 1.0f / sqrtf(red[0] / (float)C + 1e-6f);
#pragma unroll
  for (int u = 0; u < CPT; u++) {
    int c = t + u * bs;
    float yv = (xv[u] - mean) * inv * g[c] + be[c];
    out[(size_t)row * C + c] = fmaxf(yv, 0.f);
  }
}

// =================== pool (max over 4 NN) + row-select ===================
__global__ void pool_select_kernel(const float* __restrict__ fm, const int* __restrict__ idx4,
                                   const int* __restrict__ sel, const float* __restrict__ vin,
                                   float* __restrict__ vout, float* __restrict__ out,
                                   int N, int M, int C) {
  int row = blockIdx.x; int b = row / M, r = row - b * M;
  int s = sel[r];
  const int* id = idx4 + ((size_t)b * N + s) * 4;
  int i0 = id[0], i1 = id[1], i2 = id[2], i3 = id[3];
  const float* fb = fm + (size_t)b * N * C;
  for (int c = threadIdx.x; c < C; c += blockDim.x) {
    float m = fmaxf(fmaxf(fb[(size_t)i0 * C + c], fb[(size_t)i1 * C + c]),
                    fmaxf(fb[(size_t)i2 * C + c], fb[(size_t)i3 * C + c]));
    out[((size_t)b * M + r) * C + c] = m;
  }
  if (vout != nullptr && threadIdx.x < 3)
    vout[((size_t)b * M + r) * 3 + threadIdx.x] = vin[((size_t)b * N + s) * 3 + threadIdx.x];
}

// =================== token transpose ===================
__global__ void tok_kernel(const float* __restrict__ token, float* __restrict__ tok) {
  int id = blockIdx.x * 256 + threadIdx.x;
  int e = id & 63; int n = (id >> 6) & 1023;
  tok[id] = token[e * 1024 + n];
}

// =================== linear: y = x(R,I) @ W(O,I)^T + bias (+res) ===================
__global__ void linear_oi_kernel(const float* __restrict__ x, const float* __restrict__ W,
                                 const float* __restrict__ bias, const float* __restrict__ res,
                                 float* __restrict__ y, int R, int I, int O) {
  int rb = blockIdx.x * 8;
  int o = threadIdx.x;
  __shared__ float xs[8][256];
  for (int u = 0; u < 8; u++)
    for (int i2 = threadIdx.x; i2 < I; i2 += O) xs[u][i2] = x[(size_t)(rb + u) * I + i2];
  __syncthreads();
  float a[8] = {0, 0, 0, 0, 0, 0, 0, 0};
  const float* w = W + (size_t)o * I;
  for (int k2 = 0; k2 < I; k2++) {
    float wv = w[k2];
#pragma unroll
    for (int u = 0; u < 8; u++) a[u] += xs[u][k2] * wv;
  }
  float bv = bias[o];
#pragma unroll
  for (int u = 0; u < 8; u++) {
    float val = a[u] + bv;
    if (res) val += res[(size_t)(rb + u) * O + o];
    y[(size_t)(rb + u) * O + o] = val;
  }
}

// =================== tiled flash attention ===================
// 256 threads = QG q-groups x KS k-split x 2 d-split.  Each thread owns QPT
// q rows (half head-dim each), online-softmax in registers, K/V tiles in LDS.
// LDS stride padded to HD/4+1 float4 -> <=2-way bank aliasing (free, m136).
template <int HD, int QPT, int KS>
__global__ __launch_bounds__(256) void attn_tiled(
    const float* __restrict__ q, const float* __restrict__ kk,
    const float* __restrict__ vv, float* __restrict__ o,
    int Lq, int Lk, int H, float scale) {
  constexpr int TK = 64;            // k rows per LDS tile
  constexpr int QG = 256 / (2 * KS);
  constexpr int QPB = QG * QPT;     // q rows per block
  constexpr int V4 = HD / 4;        // float4 per full K/V row
  constexpr int STR = V4 + 1;       // padded LDS stride (float4)
  constexpr int HH = HD / 2;        // dims owned per lane
  constexpr int V4H = HH / 4;

  __shared__ float4 Ks[TK * STR];
  __shared__ float4 Vs[TK * STR];

  int t = threadIdx.x;
  int dh = t & 1;
  int ki = (t >> 1) & (KS - 1);
  int qg = t / (2 * KS);
  int nqt = Lq / QPB;
  int qt = blockIdx.x % nqt, bh = blockIdx.x / nqt;
  int h = bh % H, b = bh / H;
  int E = H * HD;
  int q0 = qt * QPB + qg * QPT;

  const float* qbase = q + ((size_t)b * Lq + q0) * E + h * HD + dh * HH;
  const float* kbase = kk + (size_t)b * Lk * E + h * HD;
  const float* vbase = vv + (size_t)b * Lk * E + h * HD;

  float qr[QPT][HH], O[QPT][HH], m[QPT], l[QPT];
#pragma unroll
  for (int r = 0; r < QPT; r++) {
    m[r] = -FINF; l[r] = 0.f;
#pragma unroll
    for (int d = 0; d < HH; d++) { qr[r][d] = qbase[(size_t)r * E + d]; O[r][d] = 0.f; }
  }

  for (int k0 = 0; k0 < Lk; k0 += TK) {
    __syncthreads();
    for (int e = t; e < TK * V4; e += 256) {
      int rr = e / V4, cc = e - rr * V4;
      Ks[rr * STR + cc] = *(const float4*)(kbase + (size_t)(k0 + rr) * E + cc * 4);
      Vs[rr * STR + cc] = *(const float4*)(vbase + (size_t)(k0 + rr) * E + cc * 4);
    }
    __syncthreads();
#pragma unroll 1
    for (int g = 0; g < TK / KS; g += 4) {
      float sc[QPT][4];
#pragma unroll
      for (int jj = 0; jj < 4; jj++) {
        int kl = (g + jj) * KS + ki;
        float sh[QPT];
#pragma unroll
        for (int r = 0; r < QPT; r++) sh[r] = 0.f;
        const float4* kr = &Ks[kl * STR + dh * V4H];
#pragma unroll
        for (int c = 0; c < V4H; c++) {
          float4 kv = kr[c];
#pragma unroll
          for (int r = 0; r < QPT; r++)
            sh[r] += qr[r][4 * c] * kv.x + qr[r][4 * c + 1] * kv.y
                   + qr[r][4 * c + 2] * kv.z + qr[r][4 * c + 3] * kv.w;
        }
#pragma unroll
        for (int r = 0; r < QPT; r++)
          sc[r][jj] = (sh[r] + __shfl_xor(sh[r], 1)) * scale;
      }
#pragma unroll
      for (int r = 0; r < QPT; r++) {
        float tm = fmaxf(fmaxf(sc[r][0], sc[r][1]), fmaxf(sc[r][2], sc[r][3]));
        float nm = fmaxf(m[r], tm);
        float a = __expf(m[r] - nm);   // first group: exp(-inf)=0, O,l already 0
        m[r] = nm;
        float ls = l[r] * a;
#pragma unroll
        for (int d = 0; d < HH; d++) O[r][d] *= a;
#pragma unroll
        for (int jj = 0; jj < 4; jj++) { sc[r][jj] = __expf(sc[r][jj] - nm); ls += sc[r][jj]; }
        l[r] = ls;
      }
#pragma unroll
      for (int jj = 0; jj < 4; jj++) {
        int kl = (g + jj) * KS + ki;
        const float4* vr = &Vs[kl * STR + dh * V4H];
#pragma unroll
        for (int c = 0; c < V4H; c++) {
          float4 v4 = vr[c];
#pragma unroll
          for (int r = 0; r < QPT; r++) {
            O[r][4 * c]     += sc[r][jj] * v4.x;
            O[r][4 * c + 1] += sc[r][jj] * v4.y;
            O[r][4 * c + 2] += sc[r][jj] * v4.z;
            O[r][4 * c + 3] += sc[r][jj] * v4.w;
          }
        }
      }
    }
  }
  // combine the KS partials (lane xor masks 2..KS)
#pragma unroll
  for (int r = 0; r < QPT; r++) {
    float M = m[r];
#pragma unroll
    for (int mask = 2; mask < 2 * KS; mask <<= 1) M = fmaxf(M, __shfl_xor(M, mask));
    float w = __expf(m[r] - M);
    float ll = l[r] * w;
#pragma unroll
    for (int mask = 2; mask < 2 * KS; mask <<= 1) ll += __shfl_xor(ll, mask);
    float inv = 1.f / ll;
#pragma unroll
    for (int d = 0; d < HH; d++) {
      float x = O[r][d] * w;
#pragma unroll
      for (int mask = 2; mask < 2 * KS; mask <<= 1) x += __shfl_xor(x, mask);
      O[r][d] = x * inv;
    }
  }
  if (ki == 0) {
    float* obase = o + ((size_t)b * Lq + q0) * E + h * HD + dh * HH;
#pragma unroll
    for (int r = 0; r < QPT; r++)
#pragma unroll
      for (int d = 0; d < HH; d++) obase[(size_t)r * E + d] = O[r][d];
  }
}

// =================== BN (train-mode) stats & apply ===================
__global__ void bn_stats_kernel(const float* __restrict__ x, float* __restrict__ stats,
                                int R, int C) {
  int c = blockIdx.x; int t = threadIdx.x;
  __shared__ float red[8];
  float s = 0.f;
  for (int r = t; r < R; r += blockDim.x) s += x[(size_t)r * C + c];
  for (int off = 32; off; off >>= 1) s += __shfl_down(s, off);
  if ((t & 63) == 0) red[t >> 6] = s;
  __syncthreads();
  if (t == 0) { float a = red[0]; for (int w = 1; w < (int)(blockDim.x >> 6); w++) a += red[w]; red[0] = a; }
  __syncthreads();
  float mean = red[0] / (float)R;
  __syncthreads();
  float s2 = 0.f;
  for (int r = t; r < R; r += blockDim.x) { float d = x[(size_t)r * C + c] - mean; s2 += d * d; }
  for (int off = 32; off; off >>= 1) s2 += __shfl_down(s2, off);
  if ((t & 63) == 0) red[t >> 6] = s2;
  __syncthreads();
  if (t == 0) {
    float a = red[0]; for (int w = 1; w < (int)(blockDim.x >> 6); w++) a += red[w];
    stats[c] = mean; stats[C + c] = a / (float)R;
  }
}

__global__ void bn_apply_kernel(float* __restrict__ x, const float* __restrict__ stats,
                                const float* __restrict__ g, const float* __restrict__ b2,
                                int total, int C) {
  int id = blockIdx.x * blockDim.x + threadIdx.x;
  if (id >= total) return;
  int c = id % C;
  float y = (x[id] - stats[c]) / sqrtf(stats[C + c] + 1e-5f) * g[c] + b2[c];
  x[id] = fmaxf(y, 0.f);
}

// =================== final conv1x1 ===================
__global__ void final_kernel(const float* __restrict__ fmf, const float* __restrict__ W,
                             const float* __restrict__ bias, float* __restrict__ out) {
  int nb = blockIdx.x * 8;
  int o = threadIdx.x;
  __shared__ float xs[8][1024];
  for (int u = 0; u < 8; u++)
    for (int c = threadIdx.x; c < 1024; c += 256) xs[u][c] = fmf[(size_t)(nb + u) * 1024 + c];
  __syncthreads();
  float acc[8] = {0, 0, 0, 0, 0, 0, 0, 0};
  const float* w = W + (size_t)o * 1024;
  for (int c = 0; c < 1024; c++) {
    float wv = w[c];
#pragma unroll
    for (int u = 0; u < 8; u++) acc[u] += xs[u][c] * wv;
  }
  float bv = bias[o];
#pragma unroll
  for (int u = 0; u < 8; u++) {
    int r = nb + u; int b = r >> 10; int n = r & 1023;
    out[((size_t)(b * 256 + o) << 10) + n] = acc[u] + bv;
  }
}

// =================== launch ===================
extern "C" void kernel_launch(void* const* d_in, const int* in_sizes, int n_in,
                              void* d_out, int out_size, void* d_ws, size_t ws_size,
                              hipStream_t stream) {
  (void)in_sizes; (void)n_in; (void)out_size;
  const float* vertices = (const float*)d_in[0];
  const float* d0       = (const float*)d_in[1];
  const float* g0       = (const float*)d_in[2];
  const float* be0      = (const float*)d_in[3];
  const float* w1       = (const float*)d_in[4];
  const float* b1       = (const float*)d_in[5];
  const float* dir1     = (const float*)d_in[6];
  const float* g1       = (const float*)d_in[7];
  const float* be1      = (const float*)d_in[8];
  const float* w2       = (const float*)d_in[9];
  const float* b2       = (const float*)d_in[10];
  const float* dir2     = (const float*)d_in[11];
  const float* g2       = (const float*)d_in[12];
  const float* be2      = (const float*)d_in[13];
  const float* w3       = (const float*)d_in[14];
  const float* b3       = (const float*)d_in[15];
  const float* dir3     = (const float*)d_in[16];
  const float* g3       = (const float*)d_in[17];
  const float* be3      = (const float*)d_in[18];
  const float* token    = (const float*)d_in[19];
  const float* a1_in_w  = (const float*)d_in[20];
  const float* a1_in_b  = (const float*)d_in[21];
  const float* a1_out_w = (const float*)d_in[22];
  const float* a1_out_b = (const float*)d_in[23];
  const float* ffn1_w   = (const float*)d_in[24];
  const float* ffn1_b   = (const float*)d_in[25];
  const float* bg       = (const float*)d_in[26];
  const float* bbp      = (const float*)d_in[27];
  const float* ffn2_w   = (const float*)d_in[28];
  const float* ffn2_b   = (const float*)d_in[29];
  const float* a2_in_w  = (const float*)d_in[30];
  const float* a2_in_b  = (const float*)d_in[31];
  const float* a2_out_w = (const float*)d_in[32];
  const float* a2_out_b = (const float*)d_in[33];
  const float* w7       = (const float*)d_in[34];
  const float* b7       = (const float*)d_in[35];
  const float* dir7     = (const float*)d_in[36];
  const float* g4       = (const float*)d_in[37];
  const float* be4      = (const float*)d_in[38];
  const float* c8_w     = (const float*)d_in[39];
  const float* c8_b     = (const float*)d_in[40];
  float* out = (float*)d_out;
  float* ws = (float*)d_ws;

  if (ws_size < 78568448u) return;

  float* FO     = ws + 0;
  float* S1     = ws + 8388608;
  float* S2     = ws + 12582912;
  float* S3     = ws + 13631488;
  float* QUERY2 = ws + 14680064;
  float* CROSS  = ws + 15728640;
  float* FM1P   = ws + 16777216;
  float* FM3P   = FM1P + 262144;
  float* TOK    = FM3P + 262144;
  float* Q1     = TOK + 262144;
  float* K1     = Q1 + 262144;
  float* VA1    = K1 + 262144;
  float* ATT1   = VA1 + 262144;
  float* K2     = ATT1 + 262144;
  float* V2     = K2 + 262144;
  float* V1     = V2 + 262144;
  float* BNST   = V1 + 12288;
  int* IDX20_0  = (int*)(BNST + 512);
  int* IDX4_0   = IDX20_0 + 327680;
  int* IDX20_1  = IDX4_0 + 65536;
  int* IDX4_1   = IDX20_1 + 81920;
  int* SEL1     = IDX4_1 + 16384;
  int* SEL2     = SEL1 + 1024;

  perm_kernel<<<1, 1024, 0, stream>>>(1u, 4096, 2, 1024, SEL1, 1);
  perm_kernel<<<1, 1024, 0, stream>>>(2u, 1024, 1, 256, SEL2, 1);

  knn_kernel<16><<<4 * 4096, 256, 0, stream>>>(vertices, 4096, IDX20_0, IDX4_0);
  conv_surface_kernel<<<4 * 4096, 64, 0, stream>>>(vertices, IDX20_0, d0, g0, be0, S2, 4096);
  gemm_io_kernel<<<dim3(2048, 1), 128, 0, stream>>>(S2, w1, b1, FO, 16384, 32, 128);
  combine_kernel<1><<<16384, 64, 0, stream>>>(vertices, IDX20_0, FO, dir1, g1, be1, S1, 4096, 64);
  pool_select_kernel<<<4096, 64, 0, stream>>>(S1, IDX4_0, SEL1, vertices, V1, FM1P, 4096, 1024, 64);

  knn_kernel<4><<<4 * 1024, 256, 0, stream>>>(V1, 1024, IDX20_1, IDX4_1);
  gemm_io_kernel<<<dim3(512, 1), 256, 0, stream>>>(FM1P, w2, b2, FO, 4096, 64, 256);
  combine_kernel<1><<<4096, 128, 0, stream>>>(V1, IDX20_1, FO, dir2, g2, be2, S2, 1024, 128);
  gemm_io_kernel<<<dim3(512, 2), 256, 0, stream>>>(S2, w3, b3, FO, 4096, 128, 512);
  combine_kernel<1><<<4096, 256, 0, stream>>>(V1, IDX20_1, FO, dir3, g3, be3, S3, 1024, 256);
  pool_select_kernel<<<1024, 256, 0, stream>>>(S3, IDX4_1, SEL2, nullptr, nullptr, FM3P, 1024, 256, 256);

  // MHA1 (tok as Q, fm1p as KV) + residual
  tok_kernel<<<1024, 256, 0, stream>>>(token, TOK);
  linear_oi_kernel<<<512, 64, 0, stream>>>(TOK, a1_in_w, a1_in_b, nullptr, Q1, 4096, 64, 64);
  linear_oi_kernel<<<512, 64, 0, stream>>>(FM1P, a1_in_w + 64 * 64, a1_in_b + 64, nullptr, K1, 4096, 64, 64);
  linear_oi_kernel<<<512, 64, 0, stream>>>(FM1P, a1_in_w + 128 * 64, a1_in_b + 128, nullptr, VA1, 4096, 64, 64);
  // HD=16, QPT=4, KS=8 -> QPB=64 -> grid 16*16
  attn_tiled<16, 4, 8><<<256, 256, 0, stream>>>(Q1, K1, VA1, ATT1, 1024, 1024, 4, 0.25f);
  linear_oi_kernel<<<512, 64, 0, stream>>>(ATT1, a1_out_w, a1_out_b, FM1P, S3, 4096, 64, 64);

  // FFN
  linear_oi_kernel<<<512, 256, 0, stream>>>(S3, ffn1_w, ffn1_b, nullptr, S2, 4096, 64, 256);
  bn_stats_kernel<<<256, 256, 0, stream>>>(S2, BNST, 4096, 256);
  bn_apply_kernel<<<4096, 256, 0, stream>>>(S2, BNST, bg, bbp, 4096 * 256, 256);
  linear_oi_kernel<<<512, 256, 0, stream>>>(S2, ffn2_w, ffn2_b, nullptr, QUERY2, 4096, 256, 256);

  // MHA2 (query2 as Q, fm3p as KV) + residual
  linear_oi_kernel<<<512, 256, 0, stream>>>(QUERY2, a2_in_w, a2_in_b, nullptr, S3, 4096, 256, 256);
  linear_oi_kernel<<<128, 256, 0, stream>>>(FM3P, a2_in_w + 256 * 256, a2_in_b + 256, nullptr, K2, 1024, 256, 256);
  linear_oi_kernel<<<128, 256, 0, stream>>>(FM3P, a2_in_w + 512 * 256, a2_in_b + 512, nullptr, V2, 1024, 256, 256);
  // HD=64, QPT=2, KS=8 -> QPB=32 -> grid 32*16
  attn_tiled<64, 2, 8><<<512, 256, 0, stream>>>(S3, K2, V2, S1, 1024, 256, 4, 0.125f);
  linear_oi_kernel<<<512, 256, 0, stream>>>(S1, a2_out_w, a2_out_b, QUERY2, CROSS, 4096, 256, 256);

  // conv_layer7 + final conv1x1
  gemm_io_kernel<<<dim3(512, 8), 256, 0, stream>>>(CROSS, w7, b7, FO, 4096, 256, 2048);
  combine_kernel<4><<<4096, 256, 0, stream>>>(V1, IDX20_1, FO, dir7, g4, be4, S1, 1024, 1024);
  final_kernel<<<512, 256, 0, stream>>>(S1, c8_w, c8_b, out);
}

// Round 3
// 1148.754 us; speedup vs baseline: 2.5349x; 1.3000x over previous
//
#include <hip/hip_runtime.h>
#include <stdint.h>
#include <stddef.h>

#define FINF __builtin_inff()

// =================== Threefry-2x32 (JAX-compatible) ===================
__device__ inline void tf2x32(uint32_t k0, uint32_t k1, uint32_t x0, uint32_t x1,
                              uint32_t* o0, uint32_t* o1) {
  uint32_t ks2 = k0 ^ k1 ^ 0x1BD11BDAu;
  uint32_t v0 = x0 + k0, v1 = x1 + k1;
#define TFR(r) { v0 += v1; v1 = (v1 << (r)) | (v1 >> (32 - (r))); v1 ^= v0; }
  TFR(13) TFR(15) TFR(26) TFR(6)
  v0 += k1;  v1 += ks2 + 1u;
  TFR(17) TFR(29) TFR(16) TFR(24)
  v0 += ks2; v1 += k0 + 2u;
  TFR(13) TFR(15) TFR(26) TFR(6)
  v0 += k0;  v1 += k1 + 3u;
  TFR(17) TFR(29) TFR(16) TFR(24)
  v0 += k1;  v1 += ks2 + 4u;
  TFR(13) TFR(15) TFR(26) TFR(6)
  v0 += ks2; v1 += k0 + 5u;
#undef TFR
  *o0 = v0; *o1 = v1;
}

// Both jax.random.permutation prefixes in one dispatch (block 0: seed1/n4096,
// block 1: seed2/n1024).  Sort-based shuffle, stable (pos embedded in key).
__global__ __launch_bounds__(1024) void perm_both_kernel(int* __restrict__ sel1,
                                                         int* __restrict__ sel2) {
  __shared__ unsigned long long keys[4096];
  __shared__ int vals[4096];
  __shared__ uint32_t kst[2];
  __shared__ uint32_t sk[2];
  uint32_t seed = (blockIdx.x == 0) ? 1u : 2u;
  int n       = (blockIdx.x == 0) ? 4096 : 1024;
  int rounds  = (blockIdx.x == 0) ? 2 : 1;
  int m       = (blockIdx.x == 0) ? 1024 : 256;
  int* out    = (blockIdx.x == 0) ? sel1 : sel2;
  int t = threadIdx.x;
  for (int i = t; i < n; i += 1024) vals[i] = i;
  if (t == 0) { kst[0] = 0u; kst[1] = seed; }
  __syncthreads();
  for (int r = 0; r < rounds; r++) {
    if (t == 0) {
      uint32_t a0, a1, b0, b1;
      tf2x32(kst[0], kst[1], 0u, 0u, &a0, &a1);  // new key
      tf2x32(kst[0], kst[1], 0u, 1u, &b0, &b1);  // subkey
      kst[0] = a0; kst[1] = a1; sk[0] = b0; sk[1] = b1;
    }
    __syncthreads();
    uint32_t s0 = sk[0], s1 = sk[1];
    for (int i = t; i < n; i += 1024) {
      uint32_t y0, y1; tf2x32(s0, s1, 0u, (uint32_t)i, &y0, &y1);
      keys[i] = ((unsigned long long)(y0 ^ y1) << 32) | (unsigned)i;
    }
    __syncthreads();
    for (int kk = 2; kk <= n; kk <<= 1) {
      for (int j = kk >> 1; j > 0; j >>= 1) {
        for (int i = t; i < n; i += 1024) {
          int l = i ^ j;
          if (l > i) {
            unsigned long long ki = keys[i], kl = keys[l];
            bool up = ((i & kk) == 0);
            if (up ? (ki > kl) : (ki < kl)) {
              keys[i] = kl; keys[l] = ki;
              int v = vals[i]; vals[i] = vals[l]; vals[l] = v;
            }
          }
        }
        __syncthreads();
      }
    }
  }
  for (int i = t; i < m; i += 1024) out[i] = vals[i];
}

// =================== KNN: barrier-free per-wave top-21 + rank merge ===========
// Block = 4 waves, one query row.  Wave w owns candidates j = w*(N/4)+m*64+lane.
// Per lane: bitonic-sort CNT candidates in registers (compile-time network),
// then 21 shfl-argmin rounds pop per-lane sorted queues (no block barriers).
// One barrier, then lane-parallel rank merge of the 4 sorted 21-lists.
// Rank 0 is self (diagonal dist is exact 0, strict min for random points);
// ranks 1..20 -> idx20, ranks 1..4 -> idx4 (consumers reduce over k with max,
// so rank-slot assignment order is all that matters).
template <int CNT>
__global__ __launch_bounds__(256) void knn_sel_kernel(const float* __restrict__ verts, int N,
                                                      int* __restrict__ idx20,
                                                      int* __restrict__ idx4) {
  int row = blockIdx.x; int b = row / N, i = row - b * N;
  int t = threadIdx.x; int w = t >> 6; int lane = t & 63;
  const float* vb = verts + (size_t)b * N * 3;
  float xi = vb[i * 3], yi = vb[i * 3 + 1], zi = vb[i * 3 + 2];
  float sqi = (xi * xi + yi * yi) + zi * zi;

  int base = w * (N >> 2) + lane;
  float qd[CNT]; int qi[CNT];
#pragma unroll
  for (int m = 0; m < CNT; m++) {
    int j = base + m * 64;
    float xj = vb[j * 3], yj = vb[j * 3 + 1], zj = vb[j * 3 + 2];
    float sqj = (xj * xj + yj * yj) + zj * zj;
    float dot = (xi * xj + yi * yj) + zi * zj;
    qd[m] = sqi + sqj - 2.f * dot;
    qi[m] = j;
  }
  // register bitonic sort ascending on dist (ties ~impossible for random pts)
#pragma unroll
  for (int k = 2; k <= CNT; k <<= 1)
#pragma unroll
    for (int j = k >> 1; j > 0; j >>= 1)
#pragma unroll
      for (int m = 0; m < CNT; m++) {
        int l = m ^ j;
        if (l > m) {
          bool up = ((m & k) == 0);
          bool sw = up ? (qd[m] > qd[l]) : (qd[m] < qd[l]);
          float td = sw ? qd[l] : qd[m]; qd[l] = sw ? qd[m] : qd[l]; qd[m] = td;
          int ti = sw ? qi[l] : qi[m]; qi[l] = sw ? qi[m] : qi[l]; qi[m] = ti;
        }
      }

  __shared__ float wd[4][21];
  __shared__ int wi[4][21];
  // 21 extraction rounds, wave-local (no barriers)
  for (int r = 0; r < 21; r++) {
    float hd = qd[0]; int hi = qi[0];
#pragma unroll
    for (int off = 1; off < 64; off <<= 1) {
      float od = __shfl_xor(hd, off); int oi = __shfl_xor(hi, off);
      if (od < hd || (od == hd && oi < hi)) { hd = od; hi = oi; }
    }
    if (lane == 0) { wd[w][r] = hd; wi[w][r] = hi; }
    bool win = (qi[0] == hi);
#pragma unroll
    for (int m = 0; m < CNT - 1; m++) {
      qd[m] = win ? qd[m + 1] : qd[m];
      qi[m] = win ? qi[m + 1] : qi[m];
    }
    if (win) { qd[CNT - 1] = FINF; qi[CNT - 1] = 0x7fffffff; }
  }
  __syncthreads();
  // rank merge: element (w, lane) for lane<21
  if (lane < 21) {
    float d0 = wd[w][lane]; int i0 = wi[w][lane];
    int rank = lane;
#pragma unroll
    for (int w2 = 0; w2 < 4; w2++) {
      if (w2 == w) continue;
      for (int p = 0; p < 21; p++) {
        float ld = wd[w2][p]; int li = wi[w2][p];
        rank += (ld < d0 || (ld == d0 && li < i0)) ? 1 : 0;
      }
    }
    if (rank >= 1 && rank <= 20) idx20[(size_t)row * 20 + (rank - 1)] = i0;
    if (rank >= 1 && rank <= 4)  idx4[(size_t)row * 4 + (rank - 1)] = i0;
  }
}

// =================== conv_surface + LN + relu -> fm0 (C=32) ===================
__global__ void conv_surface_kernel(const float* __restrict__ verts,
                                    const int* __restrict__ idx20,
                                    const float* __restrict__ d0,
                                    const float* __restrict__ g, const float* __restrict__ be,
                                    float* __restrict__ out, int N) {
  int row = blockIdx.x; int b = row / N, i = row - b * N;
  int t = threadIdx.x;
  __shared__ float nd[20][3];
  const float* vb = verts + (size_t)b * N * 3;
  if (t < 20) {
    int j = idx20[(size_t)row * 20 + t];
    float dx = vb[j * 3] - vb[i * 3], dy = vb[j * 3 + 1] - vb[i * 3 + 1], dz = vb[j * 3 + 2] - vb[i * 3 + 2];
    float n2 = sqrtf(dx * dx + dy * dy + dz * dz); n2 = fmaxf(n2, 1e-12f);
    nd[t][0] = dx / n2; nd[t][1] = dy / n2; nd[t][2] = dz / n2;
  }
  __syncthreads();
  float x = 0.f;
  if (t < 32) {
    float a = d0[t], bb2 = d0[32 + t], c = d0[64 + t];
    float nrm = fmaxf(sqrtf(a * a + bb2 * bb2 + c * c), 1e-12f);
    a /= nrm; bb2 /= nrm; c /= nrm;
    float mx = -FINF;
    for (int kk = 0; kk < 20; kk++) {
      float th = fmaxf(nd[kk][0] * a + nd[kk][1] * bb2 + nd[kk][2] * c, 0.f);
      mx = fmaxf(mx, th);
    }
    x = mx;
  }
  float s = x;
  for (int off = 32; off; off >>= 1) s += __shfl_xor(s, off);
  float mean = s / 32.f;
  float dev = (t < 32) ? x - mean : 0.f;
  float s2 = dev * dev;
  for (int off = 32; off; off >>= 1) s2 += __shfl_xor(s2, off);
  float var = s2 / 32.f;
  if (t < 32) {
    float y = (x - mean) / sqrtf(var + 1e-6f) * g[t] + be[t];
    out[(size_t)row * 32 + t] = fmaxf(y, 0.f);
  }
}

// =================== GEMM: y = x(R,I) @ W(I,O) + bias ===================
__global__ void gemm_io_kernel(const float* __restrict__ x, const float* __restrict__ W,
                               const float* __restrict__ bias, float* __restrict__ y,
                               int R, int I, int O) {
  int rb = blockIdx.x * 8;
  int o = blockIdx.y * blockDim.x + threadIdx.x;
  __shared__ float xs[8][256];
  for (int u = 0; u < 8; u++)
    for (int i2 = threadIdx.x; i2 < I; i2 += blockDim.x) xs[u][i2] = x[(size_t)(rb + u) * I + i2];
  __syncthreads();
  float a[8] = {0, 0, 0, 0, 0, 0, 0, 0};
  for (int k2 = 0; k2 < I; k2++) {
    float wv = W[(size_t)k2 * O + o];
#pragma unroll
    for (int u = 0; u < 8; u++) a[u] += xs[u][k2] * wv;
  }
  float bv = bias[o];
#pragma unroll
  for (int u = 0; u < 8; u++) y[(size_t)(rb + u) * O + o] = a[u] + bv;
}

// =================== conv_layer combine ===================
template <int CPT>
__global__ void combine_kernel(const float* __restrict__ verts, const int* __restrict__ idx20,
                               const float* __restrict__ fo, const float* __restrict__ dirs,
                               const float* __restrict__ g, const float* __restrict__ be,
                               float* __restrict__ out, int N, int C) {
  int row = blockIdx.x; int b = row / N, i = row - b * N;
  int t = threadIdx.x, bs = blockDim.x;
  __shared__ float nd[20][3];
  __shared__ int nidx[20];
  __shared__ float red[8];
  const float* vb = verts + (size_t)b * N * 3;
  if (t < 20) {
    int j = idx20[(size_t)row * 20 + t];
    nidx[t] = j;
    float dx = vb[j * 3] - vb[i * 3], dy = vb[j * 3 + 1] - vb[i * 3 + 1], dz = vb[j * 3 + 2] - vb[i * 3 + 2];
    float n2 = fmaxf(sqrtf(dx * dx + dy * dy + dz * dz), 1e-12f);
    nd[t][0] = dx / n2; nd[t][1] = dy / n2; nd[t][2] = dz / n2;
  }
  __syncthreads();
  const float* fob = fo + (size_t)b * N * 2 * C;
  const float* forow = fob + (size_t)i * 2 * C;
  float xv[CPT];
  float ssum = 0.f;
#pragma unroll
  for (int u = 0; u < CPT; u++) {
    int c = t + u * bs;
    float da = dirs[c], db = dirs[C + c], dc = dirs[2 * C + c];
    float nrm = fmaxf(sqrtf(da * da + db * db + dc * dc), 1e-12f);
    da /= nrm; db /= nrm; dc /= nrm;
    float mx = -FINF;
    for (int kk = 0; kk < 20; kk++) {
      float th = fmaxf(nd[kk][0] * da + nd[kk][1] * db + nd[kk][2] * dc, 0.f);
      float sup = fob[(size_t)nidx[kk] * 2 * C + C + c];
      mx = fmaxf(mx, th * sup);
    }
    float val = forow[c] + mx;
    xv[u] = val; ssum += val;
  }
  int nw = bs >> 6;
  for (int off = 32; off; off >>= 1) ssum += __shfl_down(ssum, off);
  if ((t & 63) == 0) red[t >> 6] = ssum;
  __syncthreads();
  if (t == 0) { float s = red[0]; for (int w = 1; w < nw; w++) s += red[w]; red[0] = s; }
  __syncthreads();
  float mean = red[0] / (float)C;
  __syncthreads();
  float s2 = 0.f;
#pragma unroll
  for (int u = 0; u < CPT; u++) { float d2 = xv[u] - mean; s2 += d2 * d2; }
  for (int off = 32; off; off >>= 1) s2 += __shfl_down(s2, off);
  if ((t & 63) == 0) red[t >> 6] = s2;
  __syncthreads();
  if (t == 0) { float s = red[0]; for (int w = 1; w < nw; w++) s += red[w]; red[0] = s; }
  __syncthreads();
  float inv = 1.0f / sqrtf(red[0] / (float)C + 1e-6f);
#pragma unroll
  for (int u = 0; u < CPT; u++) {
    int c = t + u * bs;
    float yv = (xv[u] - mean) * inv * g[c] + be[c];
    out[(size_t)row * C + c] = fmaxf(yv, 0.f);
  }
}

// =================== pool (max over 4 NN) + row-select ===================
__global__ void pool_select_kernel(const float* __restrict__ fm, const int* __restrict__ idx4,
                                   const int* __restrict__ sel, const float* __restrict__ vin,
                                   float* __restrict__ vout, float* __restrict__ out,
                                   int N, int M, int C) {
  int row = blockIdx.x; int b = row / M, r = row - b * M;
  int s = sel[r];
  const int* id = idx4 + ((size_t)b * N + s) * 4;
  int i0 = id[0], i1 = id[1], i2 = id[2], i3 = id[3];
  const float* fb = fm + (size_t)b * N * C;
  for (int c = threadIdx.x; c < C; c += blockDim.x) {
    float m = fmaxf(fmaxf(fb[(size_t)i0 * C + c], fb[(size_t)i1 * C + c]),
                    fmaxf(fb[(size_t)i2 * C + c], fb[(size_t)i3 * C + c]));
    out[((size_t)b * M + r) * C + c] = m;
  }
  if (vout != nullptr && threadIdx.x < 3)
    vout[((size_t)b * M + r) * 3 + threadIdx.x] = vin[((size_t)b * N + s) * 3 + threadIdx.x];
}

// =================== token transpose ===================
__global__ void tok_kernel(const float* __restrict__ token, float* __restrict__ tok) {
  int id = blockIdx.x * 256 + threadIdx.x;
  int e = id & 63; int n = (id >> 6) & 1023;
  tok[id] = token[e * 1024 + n];
}

// =================== linear: y = x(R,I) @ W(O,I)^T + bias (+res) ===================
__global__ void linear_oi_kernel(const float* __restrict__ x, const float* __restrict__ W,
                                 const float* __restrict__ bias, const float* __restrict__ res,
                                 float* __restrict__ y, int R, int I, int O) {
  int rb = blockIdx.x * 8;
  int o = threadIdx.x;
  __shared__ float xs[8][256];
  for (int u = 0; u < 8; u++)
    for (int i2 = threadIdx.x; i2 < I; i2 += O) xs[u][i2] = x[(size_t)(rb + u) * I + i2];
  __syncthreads();
  float a[8] = {0, 0, 0, 0, 0, 0, 0, 0};
  const float* w = W + (size_t)o * I;
  for (int k2 = 0; k2 < I; k2++) {
    float wv = w[k2];
#pragma unroll
    for (int u = 0; u < 8; u++) a[u] += xs[u][k2] * wv;
  }
  float bv = bias[o];
#pragma unroll
  for (int u = 0; u < 8; u++) {
    float val = a[u] + bv;
    if (res) val += res[(size_t)(rb + u) * O + o];
    y[(size_t)(rb + u) * O + o] = val;
  }
}

// =================== tiled flash attention ===================
template <int HD, int QPT, int KS>
__global__ __launch_bounds__(256) void attn_tiled(
    const float* __restrict__ q, const float* __restrict__ kk,
    const float* __restrict__ vv, float* __restrict__ o,
    int Lq, int Lk, int H, float scale) {
  constexpr int TK = 64;
  constexpr int QG = 256 / (2 * KS);
  constexpr int QPB = QG * QPT;
  constexpr int V4 = HD / 4;
  constexpr int STR = V4 + 1;
  constexpr int HH = HD / 2;
  constexpr int V4H = HH / 4;

  __shared__ float4 Ks[TK * STR];
  __shared__ float4 Vs[TK * STR];

  int t = threadIdx.x;
  int dh = t & 1;
  int ki = (t >> 1) & (KS - 1);
  int qg = t / (2 * KS);
  int nqt = Lq / QPB;
  int qt = blockIdx.x % nqt, bh = blockIdx.x / nqt;
  int h = bh % H, b = bh / H;
  int E = H * HD;
  int q0 = qt * QPB + qg * QPT;

  const float* qbase = q + ((size_t)b * Lq + q0) * E + h * HD + dh * HH;
  const float* kbase = kk + (size_t)b * Lk * E + h * HD;
  const float* vbase = vv + (size_t)b * Lk * E + h * HD;

  float qr[QPT][HH], O[QPT][HH], m[QPT], l[QPT];
#pragma unroll
  for (int r = 0; r < QPT; r++) {
    m[r] = -FINF; l[r] = 0.f;
#pragma unroll
    for (int d = 0; d < HH; d++) { qr[r][d] = qbase[(size_t)r * E + d]; O[r][d] = 0.f; }
  }

  for (int k0 = 0; k0 < Lk; k0 += TK) {
    __syncthreads();
    for (int e = t; e < TK * V4; e += 256) {
      int rr = e / V4, cc = e - rr * V4;
      Ks[rr * STR + cc] = *(const float4*)(kbase + (size_t)(k0 + rr) * E + cc * 4);
      Vs[rr * STR + cc] = *(const float4*)(vbase + (size_t)(k0 + rr) * E + cc * 4);
    }
    __syncthreads();
#pragma unroll 1
    for (int g = 0; g < TK / KS; g += 4) {
      float sc[QPT][4];
#pragma unroll
      for (int jj = 0; jj < 4; jj++) {
        int kl = (g + jj) * KS + ki;
        float sh[QPT];
#pragma unroll
        for (int r = 0; r < QPT; r++) sh[r] = 0.f;
        const float4* kr = &Ks[kl * STR + dh * V4H];
#pragma unroll
        for (int c = 0; c < V4H; c++) {
          float4 kv = kr[c];
#pragma unroll
          for (int r = 0; r < QPT; r++)
            sh[r] += qr[r][4 * c] * kv.x + qr[r][4 * c + 1] * kv.y
                   + qr[r][4 * c + 2] * kv.z + qr[r][4 * c + 3] * kv.w;
        }
#pragma unroll
        for (int r = 0; r < QPT; r++)
          sc[r][jj] = (sh[r] + __shfl_xor(sh[r], 1)) * scale;
      }
#pragma unroll
      for (int r = 0; r < QPT; r++) {
        float tm = fmaxf(fmaxf(sc[r][0], sc[r][1]), fmaxf(sc[r][2], sc[r][3]));
        float nm = fmaxf(m[r], tm);
        float a = __expf(m[r] - nm);
        m[r] = nm;
        float ls = l[r] * a;
#pragma unroll
        for (int d = 0; d < HH; d++) O[r][d] *= a;
#pragma unroll
        for (int jj = 0; jj < 4; jj++) { sc[r][jj] = __expf(sc[r][jj] - nm); ls += sc[r][jj]; }
        l[r] = ls;
      }
#pragma unroll
      for (int jj = 0; jj < 4; jj++) {
        int kl = (g + jj) * KS + ki;
        const float4* vr = &Vs[kl * STR + dh * V4H];
#pragma unroll
        for (int c = 0; c < V4H; c++) {
          float4 v4 = vr[c];
#pragma unroll
          for (int r = 0; r < QPT; r++) {
            O[r][4 * c]     += sc[r][jj] * v4.x;
            O[r][4 * c + 1] += sc[r][jj] * v4.y;
            O[r][4 * c + 2] += sc[r][jj] * v4.z;
            O[r][4 * c + 3] += sc[r][jj] * v4.w;
          }
        }
      }
    }
  }
#pragma unroll
  for (int r = 0; r < QPT; r++) {
    float M = m[r];
#pragma unroll
    for (int mask = 2; mask < 2 * KS; mask <<= 1) M = fmaxf(M, __shfl_xor(M, mask));
    float w = __expf(m[r] - M);
    float ll = l[r] * w;
#pragma unroll
    for (int mask = 2; mask < 2 * KS; mask <<= 1) ll += __shfl_xor(ll, mask);
    float inv = 1.f / ll;
#pragma unroll
    for (int d = 0; d < HH; d++) {
      float x = O[r][d] * w;
#pragma unroll
      for (int mask = 2; mask < 2 * KS; mask <<= 1) x += __shfl_xor(x, mask);
      O[r][d] = x * inv;
    }
  }
  if (ki == 0) {
    float* obase = o + ((size_t)b * Lq + q0) * E + h * HD + dh * HH;
#pragma unroll
    for (int r = 0; r < QPT; r++)
#pragma unroll
      for (int d = 0; d < HH; d++) obase[(size_t)r * E + d] = O[r][d];
  }
}

// =================== BN (train-mode) stats & apply ===================
__global__ void bn_stats_kernel(const float* __restrict__ x, float* __restrict__ stats,
                                int R, int C) {
  int c = blockIdx.x; int t = threadIdx.x;
  __shared__ float red[8];
  float s = 0.f;
  for (int r = t; r < R; r += blockDim.x) s += x[(size_t)r * C + c];
  for (int off = 32; off; off >>= 1) s += __shfl_down(s, off);
  if ((t & 63) == 0) red[t >> 6] = s;
  __syncthreads();
  if (t == 0) { float a = red[0]; for (int w = 1; w < (int)(blockDim.x >> 6); w++) a += red[w]; red[0] = a; }
  __syncthreads();
  float mean = red[0] / (float)R;
  __syncthreads();
  float s2 = 0.f;
  for (int r = t; r < R; r += blockDim.x) { float d = x[(size_t)r * C + c] - mean; s2 += d * d; }
  for (int off = 32; off; off >>= 1) s2 += __shfl_down(s2, off);
  if ((t & 63) == 0) red[t >> 6] = s2;
  __syncthreads();
  if (t == 0) {
    float a = red[0]; for (int w = 1; w < (int)(blockDim.x >> 6); w++) a += red[w];
    stats[c] = mean; stats[C + c] = a / (float)R;
  }
}

__global__ void bn_apply_kernel(float* __restrict__ x, const float* __restrict__ stats,
                                const float* __restrict__ g, const float* __restrict__ b2,
                                int total, int C) {
  int id = blockIdx.x * blockDim.x + threadIdx.x;
  if (id >= total) return;
  int c = id % C;
  float y = (x[id] - stats[c]) / sqrtf(stats[C + c] + 1e-5f) * g[c] + b2[c];
  x[id] = fmaxf(y, 0.f);
}

// =================== final conv1x1 ===================
__global__ void final_kernel(const float* __restrict__ fmf, const float* __restrict__ W,
                             const float* __restrict__ bias, float* __restrict__ out) {
  int nb = blockIdx.x * 8;
  int o = threadIdx.x;
  __shared__ float xs[8][1024];
  for (int u = 0; u < 8; u++)
    for (int c = threadIdx.x; c < 1024; c += 256) xs[u][c] = fmf[(size_t)(nb + u) * 1024 + c];
  __syncthreads();
  float acc[8] = {0, 0, 0, 0, 0, 0, 0, 0};
  const float* w = W + (size_t)o * 1024;
  for (int c = 0; c < 1024; c++) {
    float wv = w[c];
#pragma unroll
    for (int u = 0; u < 8; u++) acc[u] += xs[u][c] * wv;
  }
  float bv = bias[o];
#pragma unroll
  for (int u = 0; u < 8; u++) {
    int r = nb + u; int b = r >> 10; int n = r & 1023;
    out[((size_t)(b * 256 + o) << 10) + n] = acc[u] + bv;
  }
}

// =================== launch ===================
extern "C" void kernel_launch(void* const* d_in, const int* in_sizes, int n_in,
                              void* d_out, int out_size, void* d_ws, size_t ws_size,
                              hipStream_t stream) {
  (void)in_sizes; (void)n_in; (void)out_size;
  const float* vertices = (const float*)d_in[0];
  const float* d0       = (const float*)d_in[1];
  const float* g0       = (const float*)d_in[2];
  const float* be0      = (const float*)d_in[3];
  const float* w1       = (const float*)d_in[4];
  const float* b1       = (const float*)d_in[5];
  const float* dir1     = (const float*)d_in[6];
  const float* g1       = (const float*)d_in[7];
  const float* be1      = (const float*)d_in[8];
  const float* w2       = (const float*)d_in[9];
  const float* b2       = (const float*)d_in[10];
  const float* dir2     = (const float*)d_in[11];
  const float* g2       = (const float*)d_in[12];
  const float* be2      = (const float*)d_in[13];
  const float* w3       = (const float*)d_in[14];
  const float* b3       = (const float*)d_in[15];
  const float* dir3     = (const float*)d_in[16];
  const float* g3       = (const float*)d_in[17];
  const float* be3      = (const float*)d_in[18];
  const float* token    = (const float*)d_in[19];
  const float* a1_in_w  = (const float*)d_in[20];
  const float* a1_in_b  = (const float*)d_in[21];
  const float* a1_out_w = (const float*)d_in[22];
  const float* a1_out_b = (const float*)d_in[23];
  const float* ffn1_w   = (const float*)d_in[24];
  const float* ffn1_b   = (const float*)d_in[25];
  const float* bg       = (const float*)d_in[26];
  const float* bbp      = (const float*)d_in[27];
  const float* ffn2_w   = (const float*)d_in[28];
  const float* ffn2_b   = (const float*)d_in[29];
  const float* a2_in_w  = (const float*)d_in[30];
  const float* a2_in_b  = (const float*)d_in[31];
  const float* a2_out_w = (const float*)d_in[32];
  const float* a2_out_b = (const float*)d_in[33];
  const float* w7       = (const float*)d_in[34];
  const float* b7       = (const float*)d_in[35];
  const float* dir7     = (const float*)d_in[36];
  const float* g4       = (const float*)d_in[37];
  const float* be4      = (const float*)d_in[38];
  const float* c8_w     = (const float*)d_in[39];
  const float* c8_b     = (const float*)d_in[40];
  float* out = (float*)d_out;
  float* ws = (float*)d_ws;

  if (ws_size < 78568448u) return;

  float* FO     = ws + 0;
  float* S1     = ws + 8388608;
  float* S2     = ws + 12582912;
  float* S3     = ws + 13631488;
  float* QUERY2 = ws + 14680064;
  float* CROSS  = ws + 15728640;
  float* FM1P   = ws + 16777216;
  float* FM3P   = FM1P + 262144;
  float* TOK    = FM3P + 262144;
  float* Q1     = TOK + 262144;
  float* K1     = Q1 + 262144;
  float* VA1    = K1 + 262144;
  float* ATT1   = VA1 + 262144;
  float* K2     = ATT1 + 262144;
  float* V2     = K2 + 262144;
  float* V1     = V2 + 262144;
  float* BNST   = V1 + 12288;
  int* IDX20_0  = (int*)(BNST + 512);
  int* IDX4_0   = IDX20_0 + 327680;
  int* IDX20_1  = IDX4_0 + 65536;
  int* IDX4_1   = IDX20_1 + 81920;
  int* SEL1     = IDX4_1 + 16384;
  int* SEL2     = SEL1 + 1024;

  perm_both_kernel<<<2, 1024, 0, stream>>>(SEL1, SEL2);

  knn_sel_kernel<16><<<4 * 4096, 256, 0, stream>>>(vertices, 4096, IDX20_0, IDX4_0);
  conv_surface_kernel<<<4 * 4096, 64, 0, stream>>>(vertices, IDX20_0, d0, g0, be0, S2, 4096);
  gemm_io_kernel<<<dim3(2048, 1), 128, 0, stream>>>(S2, w1, b1, FO, 16384, 32, 128);
  combine_kernel<1><<<16384, 64, 0, stream>>>(vertices, IDX20_0, FO, dir1, g1, be1, S1, 4096, 64);
  pool_select_kernel<<<4096, 64, 0, stream>>>(S1, IDX4_0, SEL1, vertices, V1, FM1P, 4096, 1024, 64);

  knn_sel_kernel<4><<<4 * 1024, 256, 0, stream>>>(V1, 1024, IDX20_1, IDX4_1);
  gemm_io_kernel<<<dim3(512, 1), 256, 0, stream>>>(FM1P, w2, b2, FO, 4096, 64, 256);
  combine_kernel<1><<<4096, 128, 0, stream>>>(V1, IDX20_1, FO, dir2, g2, be2, S2, 1024, 128);
  gemm_io_kernel<<<dim3(512, 2), 256, 0, stream>>>(S2, w3, b3, FO, 4096, 128, 512);
  combine_kernel<1><<<4096, 256, 0, stream>>>(V1, IDX20_1, FO, dir3, g3, be3, S3, 1024, 256);
  pool_select_kernel<<<1024, 256, 0, stream>>>(S3, IDX4_1, SEL2, nullptr, nullptr, FM3P, 1024, 256, 256);

  // MHA1 (tok as Q, fm1p as KV) + residual
  tok_kernel<<<1024, 256, 0, stream>>>(token, TOK);
  linear_oi_kernel<<<512, 64, 0, stream>>>(TOK, a1_in_w, a1_in_b, nullptr, Q1, 4096, 64, 64);
  linear_oi_kernel<<<512, 64, 0, stream>>>(FM1P, a1_in_w + 64 * 64, a1_in_b + 64, nullptr, K1, 4096, 64, 64);
  linear_oi_kernel<<<512, 64, 0, stream>>>(FM1P, a1_in_w + 128 * 64, a1_in_b + 128, nullptr, VA1, 4096, 64, 64);
  attn_tiled<16, 4, 8><<<256, 256, 0, stream>>>(Q1, K1, VA1, ATT1, 1024, 1024, 4, 0.25f);
  linear_oi_kernel<<<512, 64, 0, stream>>>(ATT1, a1_out_w, a1_out_b, FM1P, S3, 4096, 64, 64);

  // FFN
  linear_oi_kernel<<<512, 256, 0, stream>>>(S3, ffn1_w, ffn1_b, nullptr, S2, 4096, 64, 256);
  bn_stats_kernel<<<256, 256, 0, stream>>>(S2, BNST, 4096, 256);
  bn_apply_kernel<<<4096, 256, 0, stream>>>(S2, BNST, bg, bbp, 4096 * 256, 256);
  linear_oi_kernel<<<512, 256, 0, stream>>>(S2, ffn2_w, ffn2_b, nullptr, QUERY2, 4096, 256, 256);

  // MHA2 (query2 as Q, fm3p as KV) + residual
  linear_oi_kernel<<<512, 256, 0, stream>>>(QUERY2, a2_in_w, a2_in_b, nullptr, S3, 4096, 256, 256);
  linear_oi_kernel<<<128, 256, 0, stream>>>(FM3P, a2_in_w + 256 * 256, a2_in_b + 256, nullptr, K2, 1024, 256, 256);
  linear_oi_kernel<<<128, 256, 0, stream>>>(FM3P, a2_in_w + 512 * 256, a2_in_b + 512, nullptr, V2, 1024, 256, 256);
  attn_tiled<64, 2, 8><<<512, 256, 0, stream>>>(S3, K2, V2, S1, 1024, 256, 4, 0.125f);
  linear_oi_kernel<<<512, 256, 0, stream>>>(S1, a2_out_w, a2_out_b, QUERY2, CROSS, 4096, 256, 256);

  // conv_layer7 + final conv1x1
  gemm_io_kernel<<<dim3(512, 8), 256, 0, stream>>>(CROSS, w7, b7, FO, 4096, 256, 2048);
  combine_kernel<4><<<4096, 256, 0, stream>>>(V1, IDX20_1, FO, dir7, g4, be4, S1, 1024, 1024);
  final_kernel<<<512, 256, 0, stream>>>(S1, c8_w, c8_b, out);
}

// Round 5
// 1067.629 us; speedup vs baseline: 2.7275x; 1.0760x over previous
//
#include <hip/hip_runtime.h>
#include <stdint.h>
#include <stddef.h>

#define FINF __builtin_inff()

// =================== Threefry-2x32 (JAX-compatible) ===================
__device__ inline void tf2x32(uint32_t k0, uint32_t k1, uint32_t x0, uint32_t x1,
                              uint32_t* o0, uint32_t* o1) {
  uint32_t ks2 = k0 ^ k1 ^ 0x1BD11BDAu;
  uint32_t v0 = x0 + k0, v1 = x1 + k1;
#define TFR(r) { v0 += v1; v1 = (v1 << (r)) | (v1 >> (32 - (r))); v1 ^= v0; }
  TFR(13) TFR(15) TFR(26) TFR(6)
  v0 += k1;  v1 += ks2 + 1u;
  TFR(17) TFR(29) TFR(16) TFR(24)
  v0 += ks2; v1 += k0 + 2u;
  TFR(13) TFR(15) TFR(26) TFR(6)
  v0 += k0;  v1 += k1 + 3u;
  TFR(17) TFR(29) TFR(16) TFR(24)
  v0 += k1;  v1 += ks2 + 4u;
  TFR(13) TFR(15) TFR(26) TFR(6)
  v0 += ks2; v1 += k0 + 5u;
#undef TFR
  *o0 = v0; *o1 = v1;
}

// Both jax.random.permutation prefixes in one dispatch.
__global__ __launch_bounds__(1024) void perm_both_kernel(int* __restrict__ sel1,
                                                         int* __restrict__ sel2) {
  __shared__ unsigned long long keys[4096];
  __shared__ int vals[4096];
  __shared__ uint32_t kst[2];
  __shared__ uint32_t sk[2];
  uint32_t seed = (blockIdx.x == 0) ? 1u : 2u;
  int n       = (blockIdx.x == 0) ? 4096 : 1024;
  int rounds  = (blockIdx.x == 0) ? 2 : 1;
  int m       = (blockIdx.x == 0) ? 1024 : 256;
  int* out    = (blockIdx.x == 0) ? sel1 : sel2;
  int t = threadIdx.x;
  for (int i = t; i < n; i += 1024) vals[i] = i;
  if (t == 0) { kst[0] = 0u; kst[1] = seed; }
  __syncthreads();
  for (int r = 0; r < rounds; r++) {
    if (t == 0) {
      uint32_t a0, a1, b0, b1;
      tf2x32(kst[0], kst[1], 0u, 0u, &a0, &a1);
      tf2x32(kst[0], kst[1], 0u, 1u, &b0, &b1);
      kst[0] = a0; kst[1] = a1; sk[0] = b0; sk[1] = b1;
    }
    __syncthreads();
    uint32_t s0 = sk[0], s1 = sk[1];
    for (int i = t; i < n; i += 1024) {
      uint32_t y0, y1; tf2x32(s0, s1, 0u, (uint32_t)i, &y0, &y1);
      keys[i] = ((unsigned long long)(y0 ^ y1) << 32) | (unsigned)i;
    }
    __syncthreads();
    for (int kk = 2; kk <= n; kk <<= 1) {
      for (int j = kk >> 1; j > 0; j >>= 1) {
        for (int i = t; i < n; i += 1024) {
          int l = i ^ j;
          if (l > i) {
            unsigned long long ki = keys[i], kl = keys[l];
            bool up = ((i & kk) == 0);
            if (up ? (ki > kl) : (ki < kl)) {
              keys[i] = kl; keys[l] = ki;
              int v = vals[i]; vals[i] = vals[l]; vals[l] = v;
            }
          }
        }
        __syncthreads();
      }
    }
  }
  for (int i = t; i < m; i += 1024) out[i] = vals[i];
}

// ---- wave-wide argmin of per-lane heads, PROVEN primitives only ------------
// Phase 1: dist min via shfl_xor+fminf butterfly (fminf propagates exact input
// values, so the winner lane's head compares == M).  Phase 2: min index among
// matching lanes via shfl_xor+min butterfly.  Exact (d, idx) lex semantics.
__device__ inline void wave_argmin2(float head_d, int head_i, float* Mo, int* wio) {
  float M = head_d;
#pragma unroll
  for (int off = 1; off < 64; off <<= 1) M = fminf(M, __shfl_xor(M, off));
  int cand = (head_d == M) ? head_i : 0x7fffffff;
#pragma unroll
  for (int off = 1; off < 64; off <<= 1) cand = min(cand, __shfl_xor(cand, off));
  *Mo = M; *wio = cand;
}

// =================== KNN (N=4096): 4 waves/row + rank merge ===================
template <int CNT>
__global__ __launch_bounds__(256) void knn_lex_kernel(const float* __restrict__ verts, int N,
                                                      int* __restrict__ idx20,
                                                      int* __restrict__ idx4) {
  int row = blockIdx.x; int b = row / N, i = row - b * N;
  int t = threadIdx.x; int w = t >> 6; int lane = t & 63;
  const float* vb = verts + (size_t)b * N * 3;
  float xi = vb[i * 3], yi = vb[i * 3 + 1], zi = vb[i * 3 + 2];
  float sqi = (xi * xi + yi * yi) + zi * zi;

  int base = w * (N >> 2) + lane;
  float qd[CNT]; int qi[CNT];
#pragma unroll
  for (int m = 0; m < CNT; m++) {
    int j = base + m * 64;
    float xj = vb[j * 3], yj = vb[j * 3 + 1], zj = vb[j * 3 + 2];
    float sqj = (xj * xj + yj * yj) + zj * zj;
    float dot = (xi * xj + yi * yj) + zi * zj;
    qd[m] = sqi + sqj - 2.f * dot;
    qi[m] = j;
  }
  // per-lane register bitonic sort ascending on dist
#pragma unroll
  for (int k = 2; k <= CNT; k <<= 1)
#pragma unroll
    for (int j = k >> 1; j > 0; j >>= 1)
#pragma unroll
      for (int m = 0; m < CNT; m++) {
        int l = m ^ j;
        if (l > m) {
          bool up = ((m & k) == 0);
          bool sw = up ? (qd[m] > qd[l]) : (qd[m] < qd[l]);
          float td = sw ? qd[l] : qd[m]; qd[l] = sw ? qd[m] : qd[l]; qd[m] = td;
          int ti = sw ? qi[l] : qi[m]; qi[l] = sw ? qi[m] : qi[l]; qi[m] = ti;
        }
      }

  __shared__ float wd[4][21];
  __shared__ int wi[4][21];
  for (int r = 0; r < 21; r++) {
    float M; int widx;
    wave_argmin2(qd[0], qi[0], &M, &widx);
    if (lane == 0) { wd[w][r] = M; wi[w][r] = widx; }
    bool win = (qi[0] == widx);
#pragma unroll
    for (int m = 0; m < CNT - 1; m++) {
      qd[m] = win ? qd[m + 1] : qd[m];
      qi[m] = win ? qi[m + 1] : qi[m];
    }
    if (win) { qd[CNT - 1] = FINF; qi[CNT - 1] = 0x7fffffff; }
  }
  __syncthreads();
  // rank merge of the 4 sorted 21-lists
  if (lane < 21) {
    float d0 = wd[w][lane]; int i0 = wi[w][lane];
    int rank = lane;
#pragma unroll
    for (int w2 = 0; w2 < 4; w2++) {
      if (w2 == w) continue;
      for (int p = 0; p < 21; p++) {
        float ld = wd[w2][p]; int li = wi[w2][p];
        rank += (ld < d0 || (ld == d0 && li < i0)) ? 1 : 0;
      }
    }
    if (rank >= 1 && rank <= 20) idx20[(size_t)row * 20 + (rank - 1)] = i0;
    if (rank >= 1 && rank <= 4)  idx4[(size_t)row * 4 + (rank - 1)] = i0;
  }
}

// =================== KNN (N=1024): ONE wave/row, direct rank output ==========
template <int CNT>
__global__ __launch_bounds__(64) void knn_1w_lex_kernel(const float* __restrict__ verts, int N,
                                                        int* __restrict__ idx20,
                                                        int* __restrict__ idx4) {
  int row = blockIdx.x; int b = row / N, i = row - b * N;
  int lane = threadIdx.x;
  const float* vb = verts + (size_t)b * N * 3;
  float xi = vb[i * 3], yi = vb[i * 3 + 1], zi = vb[i * 3 + 2];
  float sqi = (xi * xi + yi * yi) + zi * zi;

  float qd[CNT]; int qi[CNT];
#pragma unroll
  for (int m = 0; m < CNT; m++) {
    int j = lane + m * 64;
    float xj = vb[j * 3], yj = vb[j * 3 + 1], zj = vb[j * 3 + 2];
    float sqj = (xj * xj + yj * yj) + zj * zj;
    float dot = (xi * xj + yi * yj) + zi * zj;
    qd[m] = sqi + sqj - 2.f * dot;
    qi[m] = j;
  }
#pragma unroll
  for (int k = 2; k <= CNT; k <<= 1)
#pragma unroll
    for (int j = k >> 1; j > 0; j >>= 1)
#pragma unroll
      for (int m = 0; m < CNT; m++) {
        int l = m ^ j;
        if (l > m) {
          bool up = ((m & k) == 0);
          bool sw = up ? (qd[m] > qd[l]) : (qd[m] < qd[l]);
          float td = sw ? qd[l] : qd[m]; qd[l] = sw ? qd[m] : qd[l]; qd[m] = td;
          int ti = sw ? qi[l] : qi[m]; qi[l] = sw ? qi[m] : qi[l]; qi[m] = ti;
        }
      }
  for (int r = 0; r < 21; r++) {
    float M; int widx;
    wave_argmin2(qd[0], qi[0], &M, &widx);
    if (lane == 0 && r >= 1) {
      idx20[(size_t)row * 20 + (r - 1)] = widx;
      if (r <= 4) idx4[(size_t)row * 4 + (r - 1)] = widx;
    }
    bool win = (qi[0] == widx);
#pragma unroll
    for (int m = 0; m < CNT - 1; m++) {
      qd[m] = win ? qd[m + 1] : qd[m];
      qi[m] = win ? qi[m + 1] : qi[m];
    }
    if (win) { qd[CNT - 1] = FINF; qi[CNT - 1] = 0x7fffffff; }
  }
}

// =================== conv_surface + LN + relu -> fm0 (C=32) ===================
__global__ void conv_surface_kernel(const float* __restrict__ verts,
                                    const int* __restrict__ idx20,
                                    const float* __restrict__ d0,
                                    const float* __restrict__ g, const float* __restrict__ be,
                                    float* __restrict__ out, int N) {
  int row = blockIdx.x; int b = row / N, i = row - b * N;
  int t = threadIdx.x;
  __shared__ float nd[20][3];
  const float* vb = verts + (size_t)b * N * 3;
  if (t < 20) {
    int j = idx20[(size_t)row * 20 + t];
    float dx = vb[j * 3] - vb[i * 3], dy = vb[j * 3 + 1] - vb[i * 3 + 1], dz = vb[j * 3 + 2] - vb[i * 3 + 2];
    float n2 = sqrtf(dx * dx + dy * dy + dz * dz); n2 = fmaxf(n2, 1e-12f);
    nd[t][0] = dx / n2; nd[t][1] = dy / n2; nd[t][2] = dz / n2;
  }
  __syncthreads();
  float x = 0.f;
  if (t < 32) {
    float a = d0[t], bb2 = d0[32 + t], c = d0[64 + t];
    float nrm = fmaxf(sqrtf(a * a + bb2 * bb2 + c * c), 1e-12f);
    a /= nrm; bb2 /= nrm; c /= nrm;
    float mx = -FINF;
    for (int kk = 0; kk < 20; kk++) {
      float th = fmaxf(nd[kk][0] * a + nd[kk][1] * bb2 + nd[kk][2] * c, 0.f);
      mx = fmaxf(mx, th);
    }
    x = mx;
  }
  float s = x;
  for (int off = 32; off; off >>= 1) s += __shfl_xor(s, off);
  float mean = s / 32.f;
  float dev = (t < 32) ? x - mean : 0.f;
  float s2 = dev * dev;
  for (int off = 32; off; off >>= 1) s2 += __shfl_xor(s2, off);
  float var = s2 / 32.f;
  if (t < 32) {
    float y = (x - mean) / sqrtf(var + 1e-6f) * g[t] + be[t];
    out[(size_t)row * 32 + t] = fmaxf(y, 0.f);
  }
}

// =================== GEMM: y = x(R,I) @ W(I,O) + bias ===================
__global__ void gemm_io_kernel(const float* __restrict__ x, const float* __restrict__ W,
                               const float* __restrict__ bias, float* __restrict__ y,
                               int R, int I, int O) {
  int rb = blockIdx.x * 8;
  int o = blockIdx.y * blockDim.x + threadIdx.x;
  __shared__ float xs[8][256];
  for (int u = 0; u < 8; u++)
    for (int i2 = threadIdx.x; i2 < I; i2 += blockDim.x) xs[u][i2] = x[(size_t)(rb + u) * I + i2];
  __syncthreads();
  float a[8] = {0, 0, 0, 0, 0, 0, 0, 0};
  for (int k2 = 0; k2 < I; k2++) {
    float wv = W[(size_t)k2 * O + o];
#pragma unroll
    for (int u = 0; u < 8; u++) a[u] += xs[u][k2] * wv;
  }
  float bv = bias[o];
#pragma unroll
  for (int u = 0; u < 8; u++) y[(size_t)(rb + u) * O + o] = a[u] + bv;
}

// =================== conv_layer combine ===================
template <int CPT>
__global__ void combine_kernel(const float* __restrict__ verts, const int* __restrict__ idx20,
                               const float* __restrict__ fo, const float* __restrict__ dirs,
                               const float* __restrict__ g, const float* __restrict__ be,
                               float* __restrict__ out, int N, int C) {
  int row = blockIdx.x; int b = row / N, i = row - b * N;
  int t = threadIdx.x, bs = blockDim.x;
  __shared__ float nd[20][3];
  __shared__ int nidx[20];
  __shared__ float red[8];
  const float* vb = verts + (size_t)b * N * 3;
  if (t < 20) {
    int j = idx20[(size_t)row * 20 + t];
    nidx[t] = j;
    float dx = vb[j * 3] - vb[i * 3], dy = vb[j * 3 + 1] - vb[i * 3 + 1], dz = vb[j * 3 + 2] - vb[i * 3 + 2];
    float n2 = fmaxf(sqrtf(dx * dx + dy * dy + dz * dz), 1e-12f);
    nd[t][0] = dx / n2; nd[t][1] = dy / n2; nd[t][2] = dz / n2;
  }
  __syncthreads();
  const float* fob = fo + (size_t)b * N * 2 * C;
  const float* forow = fob + (size_t)i * 2 * C;
  float xv[CPT];
  float ssum = 0.f;
#pragma unroll
  for (int u = 0; u < CPT; u++) {
    int c = t + u * bs;
    float da = dirs[c], db = dirs[C + c], dc = dirs[2 * C + c];
    float nrm = fmaxf(sqrtf(da * da + db * db + dc * dc), 1e-12f);
    da /= nrm; db /= nrm; dc /= nrm;
    float mx = -FINF;
    for (int kk = 0; kk < 20; kk++) {
      float th = fmaxf(nd[kk][0] * da + nd[kk][1] * db + nd[kk][2] * dc, 0.f);
      float sup = fob[(size_t)nidx[kk] * 2 * C + C + c];
      mx = fmaxf(mx, th * sup);
    }
    float val = forow[c] + mx;
    xv[u] = val; ssum += val;
  }
  int nw = bs >> 6;
  for (int off = 32; off; off >>= 1) ssum += __shfl_down(ssum, off);
  if ((t & 63) == 0) red[t >> 6] = ssum;
  __syncthreads();
  if (t == 0) { float s = red[0]; for (int w = 1; w < nw; w++) s += red[w]; red[0] = s; }
  __syncthreads();
  float mean = red[0] / (float)C;
  __syncthreads();
  float s2 = 0.f;
#pragma unroll
  for (int u = 0; u < CPT; u++) { float d2 = xv[u] - mean; s2 += d2 * d2; }
  for (int off = 32; off; off >>= 1) s2 += __shfl_down(s2, off);
  if ((t & 63) == 0) red[t >> 6] = s2;
  __syncthreads();
  if (t == 0) { float s = red[0]; for (int w = 1; w < nw; w++) s += red[w]; red[0] = s; }
  __syncthreads();
  float inv = 1.0f / sqrtf(red[0] / (float)C + 1e-6f);
#pragma unroll
  for (int u = 0; u < CPT; u++) {
    int c = t + u * bs;
    float yv = (xv[u] - mean) * inv * g[c] + be[c];
    out[(size_t)row * C + c] = fmaxf(yv, 0.f);
  }
}

// =================== pool (max over 4 NN) + row-select ===================
__global__ void pool_select_kernel(const float* __restrict__ fm, const int* __restrict__ idx4,
                                   const int* __restrict__ sel, const float* __restrict__ vin,
                                   float* __restrict__ vout, float* __restrict__ out,
                                   int N, int M, int C) {
  int row = blockIdx.x; int b = row / M, r = row - b * M;
  int s = sel[r];
  const int* id = idx4 + ((size_t)b * N + s) * 4;
  int i0 = id[0], i1 = id[1], i2 = id[2], i3 = id[3];
  const float* fb = fm + (size_t)b * N * C;
  for (int c = threadIdx.x; c < C; c += blockDim.x) {
    float m = fmaxf(fmaxf(fb[(size_t)i0 * C + c], fb[(size_t)i1 * C + c]),
                    fmaxf(fb[(size_t)i2 * C + c], fb[(size_t)i3 * C + c]));
    out[((size_t)b * M + r) * C + c] = m;
  }
  if (vout != nullptr && threadIdx.x < 3)
    vout[((size_t)b * M + r) * 3 + threadIdx.x] = vin[((size_t)b * N + s) * 3 + threadIdx.x];
}

// =================== token transpose ===================
__global__ void tok_kernel(const float* __restrict__ token, float* __restrict__ tok) {
  int id = blockIdx.x * 256 + threadIdx.x;
  int e = id & 63; int n = (id >> 6) & 1023;
  tok[id] = token[e * 1024 + n];
}

// =================== linear: y = x(R,I) @ W(O,I)^T + bias (+res) ===================
__global__ void linear_oi_kernel(const float* __restrict__ x, const float* __restrict__ W,
                                 const float* __restrict__ bias, const float* __restrict__ res,
                                 float* __restrict__ y, int R, int I, int O) {
  int rb = blockIdx.x * 8;
  int o = threadIdx.x;
  __shared__ float xs[8][256];
  for (int u = 0; u < 8; u++)
    for (int i2 = threadIdx.x; i2 < I; i2 += O) xs[u][i2] = x[(size_t)(rb + u) * I + i2];
  __syncthreads();
  float a[8] = {0, 0, 0, 0, 0, 0, 0, 0};
  const float* w = W + (size_t)o * I;
  for (int k2 = 0; k2 < I; k2++) {
    float wv = w[k2];
#pragma unroll
    for (int u = 0; u < 8; u++) a[u] += xs[u][k2] * wv;
  }
  float bv = bias[o];
#pragma unroll
  for (int u = 0; u < 8; u++) {
    float val = a[u] + bv;
    if (res) val += res[(size_t)(rb + u) * O + o];
    y[(size_t)(rb + u) * O + o] = val;
  }
}

// =================== tiled flash attention ===================
template <int HD, int QPT, int KS>
__global__ __launch_bounds__(256) void attn_tiled(
    const float* __restrict__ q, const float* __restrict__ kk,
    const float* __restrict__ vv, float* __restrict__ o,
    int Lq, int Lk, int H, float scale) {
  constexpr int TK = 64;
  constexpr int QG = 256 / (2 * KS);
  constexpr int QPB = QG * QPT;
  constexpr int V4 = HD / 4;
  constexpr int STR = V4 + 1;
  constexpr int HH = HD / 2;
  constexpr int V4H = HH / 4;

  __shared__ float4 Ks[TK * STR];
  __shared__ float4 Vs[TK * STR];

  int t = threadIdx.x;
  int dh = t & 1;
  int ki = (t >> 1) & (KS - 1);
  int qg = t / (2 * KS);
  int nqt = Lq / QPB;
  int qt = blockIdx.x % nqt, bh = blockIdx.x / nqt;
  int h = bh % H, b = bh / H;
  int E = H * HD;
  int q0 = qt * QPB + qg * QPT;

  const float* qbase = q + ((size_t)b * Lq + q0) * E + h * HD + dh * HH;
  const float* kbase = kk + (size_t)b * Lk * E + h * HD;
  const float* vbase = vv + (size_t)b * Lk * E + h * HD;

  float qr[QPT][HH], O[QPT][HH], m[QPT], l[QPT];
#pragma unroll
  for (int r = 0; r < QPT; r++) {
    m[r] = -FINF; l[r] = 0.f;
#pragma unroll
    for (int d = 0; d < HH; d++) { qr[r][d] = qbase[(size_t)r * E + d]; O[r][d] = 0.f; }
  }

  for (int k0 = 0; k0 < Lk; k0 += TK) {
    __syncthreads();
    for (int e = t; e < TK * V4; e += 256) {
      int rr = e / V4, cc = e - rr * V4;
      Ks[rr * STR + cc] = *(const float4*)(kbase + (size_t)(k0 + rr) * E + cc * 4);
      Vs[rr * STR + cc] = *(const float4*)(vbase + (size_t)(k0 + rr) * E + cc * 4);
    }
    __syncthreads();
#pragma unroll 1
    for (int g = 0; g < TK / KS; g += 4) {
      float sc[QPT][4];
#pragma unroll
      for (int jj = 0; jj < 4; jj++) {
        int kl = (g + jj) * KS + ki;
        float sh[QPT];
#pragma unroll
        for (int r = 0; r < QPT; r++) sh[r] = 0.f;
        const float4* kr = &Ks[kl * STR + dh * V4H];
#pragma unroll
        for (int c = 0; c < V4H; c++) {
          float4 kv = kr[c];
#pragma unroll
          for (int r = 0; r < QPT; r++)
            sh[r] += qr[r][4 * c] * kv.x + qr[r][4 * c + 1] * kv.y
                   + qr[r][4 * c + 2] * kv.z + qr[r][4 * c + 3] * kv.w;
        }
#pragma unroll
        for (int r = 0; r < QPT; r++)
          sc[r][jj] = (sh[r] + __shfl_xor(sh[r], 1)) * scale;
      }
#pragma unroll
      for (int r = 0; r < QPT; r++) {
        float tm = fmaxf(fmaxf(sc[r][0], sc[r][1]), fmaxf(sc[r][2], sc[r][3]));
        float nm = fmaxf(m[r], tm);
        float a = __expf(m[r] - nm);
        m[r] = nm;
        float ls = l[r] * a;
#pragma unroll
        for (int d = 0; d < HH; d++) O[r][d] *= a;
#pragma unroll
        for (int jj = 0; jj < 4; jj++) { sc[r][jj] = __expf(sc[r][jj] - nm); ls += sc[r][jj]; }
        l[r] = ls;
      }
#pragma unroll
      for (int jj = 0; jj < 4; jj++) {
        int kl = (g + jj) * KS + ki;
        const float4* vr = &Vs[kl * STR + dh * V4H];
#pragma unroll
        for (int c = 0; c < V4H; c++) {
          float4 v4 = vr[c];
#pragma unroll
          for (int r = 0; r < QPT; r++) {
            O[r][4 * c]     += sc[r][jj] * v4.x;
            O[r][4 * c + 1] += sc[r][jj] * v4.y;
            O[r][4 * c + 2] += sc[r][jj] * v4.z;
            O[r][4 * c + 3] += sc[r][jj] * v4.w;
          }
        }
      }
    }
  }
#pragma unroll
  for (int r = 0; r < QPT; r++) {
    float M = m[r];
#pragma unroll
    for (int mask = 2; mask < 2 * KS; mask <<= 1) M = fmaxf(M, __shfl_xor(M, mask));
    float w = __expf(m[r] - M);
    float ll = l[r] * w;
#pragma unroll
    for (int mask = 2; mask < 2 * KS; mask <<= 1) ll += __shfl_xor(ll, mask);
    float inv = 1.f / ll;
#pragma unroll
    for (int d = 0; d < HH; d++) {
      float x = O[r][d] * w;
#pragma unroll
      for (int mask = 2; mask < 2 * KS; mask <<= 1) x += __shfl_xor(x, mask);
      O[r][d] = x * inv;
    }
  }
  if (ki == 0) {
    float* obase = o + ((size_t)b * Lq + q0) * E + h * HD + dh * HH;
#pragma unroll
    for (int r = 0; r < QPT; r++)
#pragma unroll
      for (int d = 0; d < HH; d++) obase[(size_t)r * E + d] = O[r][d];
  }
}

// =================== BN (train-mode) stats & apply ===================
__global__ void bn_stats_kernel(const float* __restrict__ x, float* __restrict__ stats,
                                int R, int C) {
  int c = blockIdx.x; int t = threadIdx.x;
  __shared__ float red[8];
  float s = 0.f;
  for (int r = t; r < R; r += blockDim.x) s += x[(size_t)r * C + c];
  for (int off = 32; off; off >>= 1) s += __shfl_down(s, off);
  if ((t & 63) == 0) red[t >> 6] = s;
  __syncthreads();
  if (t == 0) { float a = red[0]; for (int w = 1; w < (int)(blockDim.x >> 6); w++) a += red[w]; red[0] = a; }
  __syncthreads();
  float mean = red[0] / (float)R;
  __syncthreads();
  float s2 = 0.f;
  for (int r = t; r < R; r += blockDim.x) { float d = x[(size_t)r * C + c] - mean; s2 += d * d; }
  for (int off = 32; off; off >>= 1) s2 += __shfl_down(s2, off);
  if ((t & 63) == 0) red[t >> 6] = s2;
  __syncthreads();
  if (t == 0) {
    float a = red[0]; for (int w = 1; w < (int)(blockDim.x >> 6); w++) a += red[w];
    stats[c] = mean; stats[C + c] = a / (float)R;
  }
}

__global__ void bn_apply_kernel(float* __restrict__ x, const float* __restrict__ stats,
                                const float* __restrict__ g, const float* __restrict__ b2,
                                int total, int C) {
  int id = blockIdx.x * blockDim.x + threadIdx.x;
  if (id >= total) return;
  int c = id % C;
  float y = (x[id] - stats[c]) / sqrtf(stats[C + c] + 1e-5f) * g[c] + b2[c];
  x[id] = fmaxf(y, 0.f);
}

// =================== final conv1x1 ===================
__global__ void final_kernel(const float* __restrict__ fmf, const float* __restrict__ W,
                             const float* __restrict__ bias, float* __restrict__ out) {
  int nb = blockIdx.x * 8;
  int o = threadIdx.x;
  __shared__ float xs[8][1024];
  for (int u = 0; u < 8; u++)
    for (int c = threadIdx.x; c < 1024; c += 256) xs[u][c] = fmf[(size_t)(nb + u) * 1024 + c];
  __syncthreads();
  float acc[8] = {0, 0, 0, 0, 0, 0, 0, 0};
  const float* w = W + (size_t)o * 1024;
  for (int c = 0; c < 1024; c++) {
    float wv = w[c];
#pragma unroll
    for (int u = 0; u < 8; u++) acc[u] += xs[u][c] * wv;
  }
  float bv = bias[o];
#pragma unroll
  for (int u = 0; u < 8; u++) {
    int r = nb + u; int b = r >> 10; int n = r & 1023;
    out[((size_t)(b * 256 + o) << 10) + n] = acc[u] + bv;
  }
}

// =================== launch ===================
extern "C" void kernel_launch(void* const* d_in, const int* in_sizes, int n_in,
                              void* d_out, int out_size, void* d_ws, size_t ws_size,
                              hipStream_t stream) {
  (void)in_sizes; (void)n_in; (void)out_size;
  const float* vertices = (const float*)d_in[0];
  const float* d0       = (const float*)d_in[1];
  const float* g0       = (const float*)d_in[2];
  const float* be0      = (const float*)d_in[3];
  const float* w1       = (const float*)d_in[4];
  const float* b1       = (const float*)d_in[5];
  const float* dir1     = (const float*)d_in[6];
  const float* g1       = (const float*)d_in[7];
  const float* be1      = (const float*)d_in[8];
  const float* w2       = (const float*)d_in[9];
  const float* b2       = (const float*)d_in[10];
  const float* dir2     = (const float*)d_in[11];
  const float* g2       = (const float*)d_in[12];
  const float* be2      = (const float*)d_in[13];
  const float* w3       = (const float*)d_in[14];
  const float* b3       = (const float*)d_in[15];
  const float* dir3     = (const float*)d_in[16];
  const float* g3       = (const float*)d_in[17];
  const float* be3      = (const float*)d_in[18];
  const float* token    = (const float*)d_in[19];
  const float* a1_in_w  = (const float*)d_in[20];
  const float* a1_in_b  = (const float*)d_in[21];
  const float* a1_out_w = (const float*)d_in[22];
  const float* a1_out_b = (const float*)d_in[23];
  const float* ffn1_w   = (const float*)d_in[24];
  const float* ffn1_b   = (const float*)d_in[25];
  const float* bg       = (const float*)d_in[26];
  const float* bbp      = (const float*)d_in[27];
  const float* ffn2_w   = (const float*)d_in[28];
  const float* ffn2_b   = (const float*)d_in[29];
  const float* a2_in_w  = (const float*)d_in[30];
  const float* a2_in_b  = (const float*)d_in[31];
  const float* a2_out_w = (const float*)d_in[32];
  const float* a2_out_b = (const float*)d_in[33];
  const float* w7       = (const float*)d_in[34];
  const float* b7       = (const float*)d_in[35];
  const float* dir7     = (const float*)d_in[36];
  const float* g4       = (const float*)d_in[37];
  const float* be4      = (const float*)d_in[38];
  const float* c8_w     = (const float*)d_in[39];
  const float* c8_b     = (const float*)d_in[40];
  float* out = (float*)d_out;
  float* ws = (float*)d_ws;

  if (ws_size < 78568448u) return;

  float* FO     = ws + 0;
  float* S1     = ws + 8388608;
  float* S2     = ws + 12582912;
  float* S3     = ws + 13631488;
  float* QUERY2 = ws + 14680064;
  float* CROSS  = ws + 15728640;
  float* FM1P   = ws + 16777216;
  float* FM3P   = FM1P + 262144;
  float* TOK    = FM3P + 262144;
  float* Q1     = TOK + 262144;
  float* K1     = Q1 + 262144;
  float* VA1    = K1 + 262144;
  float* ATT1   = VA1 + 262144;
  float* K2     = ATT1 + 262144;
  float* V2     = K2 + 262144;
  float* V1     = V2 + 262144;
  float* BNST   = V1 + 12288;
  int* IDX20_0  = (int*)(BNST + 512);
  int* IDX4_0   = IDX20_0 + 327680;
  int* IDX20_1  = IDX4_0 + 65536;
  int* IDX4_1   = IDX20_1 + 81920;
  int* SEL1     = IDX4_1 + 16384;
  int* SEL2     = SEL1 + 1024;

  perm_both_kernel<<<2, 1024, 0, stream>>>(SEL1, SEL2);

  knn_lex_kernel<16><<<4 * 4096, 256, 0, stream>>>(vertices, 4096, IDX20_0, IDX4_0);
  conv_surface_kernel<<<4 * 4096, 64, 0, stream>>>(vertices, IDX20_0, d0, g0, be0, S2, 4096);
  gemm_io_kernel<<<dim3(2048, 1), 128, 0, stream>>>(S2, w1, b1, FO, 16384, 32, 128);
  combine_kernel<1><<<16384, 64, 0, stream>>>(vertices, IDX20_0, FO, dir1, g1, be1, S1, 4096, 64);
  pool_select_kernel<<<4096, 64, 0, stream>>>(S1, IDX4_0, SEL1, vertices, V1, FM1P, 4096, 1024, 64);

  knn_1w_lex_kernel<16><<<4 * 1024, 64, 0, stream>>>(V1, 1024, IDX20_1, IDX4_1);
  gemm_io_kernel<<<dim3(512, 1), 256, 0, stream>>>(FM1P, w2, b2, FO, 4096, 64, 256);
  combine_kernel<1><<<4096, 128, 0, stream>>>(V1, IDX20_1, FO, dir2, g2, be2, S2, 1024, 128);
  gemm_io_kernel<<<dim3(512, 2), 256, 0, stream>>>(S2, w3, b3, FO, 4096, 128, 512);
  combine_kernel<1><<<4096, 256, 0, stream>>>(V1, IDX20_1, FO, dir3, g3, be3, S3, 1024, 256);
  pool_select_kernel<<<1024, 256, 0, stream>>>(S3, IDX4_1, SEL2, nullptr, nullptr, FM3P, 1024, 256, 256);

  // MHA1 (tok as Q, fm1p as KV) + residual
  tok_kernel<<<1024, 256, 0, stream>>>(token, TOK);
  linear_oi_kernel<<<512, 64, 0, stream>>>(TOK, a1_in_w, a1_in_b, nullptr, Q1, 4096, 64, 64);
  linear_oi_kernel<<<512, 64, 0, stream>>>(FM1P, a1_in_w + 64 * 64, a1_in_b + 64, nullptr, K1, 4096, 64, 64);
  linear_oi_kernel<<<512, 64, 0, stream>>>(FM1P, a1_in_w + 128 * 64, a1_in_b + 128, nullptr, VA1, 4096, 64, 64);
  attn_tiled<16, 4, 8><<<256, 256, 0, stream>>>(Q1, K1, VA1, ATT1, 1024, 1024, 4, 0.25f);
  linear_oi_kernel<<<512, 64, 0, stream>>>(ATT1, a1_out_w, a1_out_b, FM1P, S3, 4096, 64, 64);

  // FFN
  linear_oi_kernel<<<512, 256, 0, stream>>>(S3, ffn1_w, ffn1_b, nullptr, S2, 4096, 64, 256);
  bn_stats_kernel<<<256, 256, 0, stream>>>(S2, BNST, 4096, 256);
  bn_apply_kernel<<<4096, 256, 0, stream>>>(S2, BNST, bg, bbp, 4096 * 256, 256);
  linear_oi_kernel<<<512, 256, 0, stream>>>(S2, ffn2_w, ffn2_b, nullptr, QUERY2, 4096, 256, 256);

  // MHA2 (query2 as Q, fm3p as KV) + residual
  linear_oi_kernel<<<512, 256, 0, stream>>>(QUERY2, a2_in_w, a2_in_b, nullptr, S3, 4096, 256, 256);
  linear_oi_kernel<<<128, 256, 0, stream>>>(FM3P, a2_in_w + 256 * 256, a2_in_b + 256, nullptr, K2, 1024, 256, 256);
  linear_oi_kernel<<<128, 256, 0, stream>>>(FM3P, a2_in_w + 512 * 256, a2_in_b + 512, nullptr, V2, 1024, 256, 256);
  attn_tiled<64, 2, 8><<<512, 256, 0, stream>>>(S3, K2, V2, S1, 1024, 256, 4, 0.125f);
  linear_oi_kernel<<<512, 256, 0, stream>>>(S1, a2_out_w, a2_out_b, QUERY2, CROSS, 4096, 256, 256);

  // conv_layer7 + final conv1x1
  gemm_io_kernel<<<dim3(512, 8), 256, 0, stream>>>(CROSS, w7, b7, FO, 4096, 256, 2048);
  combine_kernel<4><<<4096, 256, 0, stream>>>(V1, IDX20_1, FO, dir7, g4, be4, S1, 1024, 1024);
  final_kernel<<<512, 256, 0, stream>>>(S1, c8_w, c8_b, out);
}

// Round 6
// 1006.210 us; speedup vs baseline: 2.8939x; 1.0610x over previous
//
#include <hip/hip_runtime.h>
#include <stdint.h>
#include <stddef.h>

#define FINF __builtin_inff()

// =================== Threefry-2x32 (JAX-compatible) ===================
__device__ inline void tf2x32(uint32_t k0, uint32_t k1, uint32_t x0, uint32_t x1,
                              uint32_t* o0, uint32_t* o1) {
  uint32_t ks2 = k0 ^ k1 ^ 0x1BD11BDAu;
  uint32_t v0 = x0 + k0, v1 = x1 + k1;
#define TFR(r) { v0 += v1; v1 = (v1 << (r)) | (v1 >> (32 - (r))); v1 ^= v0; }
  TFR(13) TFR(15) TFR(26) TFR(6)
  v0 += k1;  v1 += ks2 + 1u;
  TFR(17) TFR(29) TFR(16) TFR(24)
  v0 += ks2; v1 += k0 + 2u;
  TFR(13) TFR(15) TFR(26) TFR(6)
  v0 += k0;  v1 += k1 + 3u;
  TFR(17) TFR(29) TFR(16) TFR(24)
  v0 += k1;  v1 += ks2 + 4u;
  TFR(13) TFR(15) TFR(26) TFR(6)
  v0 += ks2; v1 += k0 + 5u;
#undef TFR
  *o0 = v0; *o1 = v1;
}

// Both jax.random.permutation prefixes in one dispatch.
__global__ __launch_bounds__(1024) void perm_both_kernel(int* __restrict__ sel1,
                                                         int* __restrict__ sel2) {
  __shared__ unsigned long long keys[4096];
  __shared__ int vals[4096];
  __shared__ uint32_t kst[2];
  __shared__ uint32_t sk[2];
  uint32_t seed = (blockIdx.x == 0) ? 1u : 2u;
  int n       = (blockIdx.x == 0) ? 4096 : 1024;
  int rounds  = (blockIdx.x == 0) ? 2 : 1;
  int m       = (blockIdx.x == 0) ? 1024 : 256;
  int* out    = (blockIdx.x == 0) ? sel1 : sel2;
  int t = threadIdx.x;
  for (int i = t; i < n; i += 1024) vals[i] = i;
  if (t == 0) { kst[0] = 0u; kst[1] = seed; }
  __syncthreads();
  for (int r = 0; r < rounds; r++) {
    if (t == 0) {
      uint32_t a0, a1, b0, b1;
      tf2x32(kst[0], kst[1], 0u, 0u, &a0, &a1);
      tf2x32(kst[0], kst[1], 0u, 1u, &b0, &b1);
      kst[0] = a0; kst[1] = a1; sk[0] = b0; sk[1] = b1;
    }
    __syncthreads();
    uint32_t s0 = sk[0], s1 = sk[1];
    for (int i = t; i < n; i += 1024) {
      uint32_t y0, y1; tf2x32(s0, s1, 0u, (uint32_t)i, &y0, &y1);
      keys[i] = ((unsigned long long)(y0 ^ y1) << 32) | (unsigned)i;
    }
    __syncthreads();
    for (int kk = 2; kk <= n; kk <<= 1) {
      for (int j = kk >> 1; j > 0; j >>= 1) {
        for (int i = t; i < n; i += 1024) {
          int l = i ^ j;
          if (l > i) {
            unsigned long long ki = keys[i], kl = keys[l];
            bool up = ((i & kk) == 0);
            if (up ? (ki > kl) : (ki < kl)) {
              keys[i] = kl; keys[l] = ki;
              int v = vals[i]; vals[i] = vals[l]; vals[l] = v;
            }
          }
        }
        __syncthreads();
      }
    }
  }
  for (int i = t; i < m; i += 1024) out[i] = vals[i];
}

// ---- wave-wide argmin of per-lane heads (proven primitives) ----------------
__device__ inline void wave_argmin2(float head_d, int head_i, float* Mo, int* wio) {
  float M = head_d;
#pragma unroll
  for (int off = 1; off < 64; off <<= 1) M = fminf(M, __shfl_xor(M, off));
  int cand = (head_d == M) ? head_i : 0x7fffffff;
#pragma unroll
  for (int off = 1; off < 64; off <<= 1) cand = min(cand, __shfl_xor(cand, off));
  *Mo = M; *wio = cand;
}

// =================== KNN (N=4096): WAVES waves/row + rank merge ===============
template <int CNT, int WAVES>
__global__ __launch_bounds__(64 * WAVES) void knn_lex_kernel(const float* __restrict__ verts,
                                                             int N,
                                                             int* __restrict__ idx20,
                                                             int* __restrict__ idx4) {
  int row = blockIdx.x; int b = row / N, i = row - b * N;
  int t = threadIdx.x; int w = t >> 6; int lane = t & 63;
  const float* vb = verts + (size_t)b * N * 3;
  float xi = vb[i * 3], yi = vb[i * 3 + 1], zi = vb[i * 3 + 2];
  float sqi = (xi * xi + yi * yi) + zi * zi;

  int base = w * (N / WAVES) + lane;
  float qd[CNT]; int qi[CNT];
#pragma unroll
  for (int m = 0; m < CNT; m++) {
    int j = base + m * 64;
    float xj = vb[j * 3], yj = vb[j * 3 + 1], zj = vb[j * 3 + 2];
    float sqj = (xj * xj + yj * yj) + zj * zj;
    float dot = (xi * xj + yi * yj) + zi * zj;
    qd[m] = sqi + sqj - 2.f * dot;
    qi[m] = j;
  }
  // per-lane register bitonic sort ascending on dist
#pragma unroll
  for (int k = 2; k <= CNT; k <<= 1)
#pragma unroll
    for (int j = k >> 1; j > 0; j >>= 1)
#pragma unroll
      for (int m = 0; m < CNT; m++) {
        int l = m ^ j;
        if (l > m) {
          bool up = ((m & k) == 0);
          bool sw = up ? (qd[m] > qd[l]) : (qd[m] < qd[l]);
          float td = sw ? qd[l] : qd[m]; qd[l] = sw ? qd[m] : qd[l]; qd[m] = td;
          int ti = sw ? qi[l] : qi[m]; qi[l] = sw ? qi[m] : qi[l]; qi[m] = ti;
        }
      }

  __shared__ float wd[WAVES][21];
  __shared__ int wi[WAVES][21];
  for (int r = 0; r < 21; r++) {
    float M; int widx;
    wave_argmin2(qd[0], qi[0], &M, &widx);
    if (lane == 0) { wd[w][r] = M; wi[w][r] = widx; }
    bool win = (qi[0] == widx);
#pragma unroll
    for (int m = 0; m < CNT - 1; m++) {
      qd[m] = win ? qd[m + 1] : qd[m];
      qi[m] = win ? qi[m + 1] : qi[m];
    }
    if (win) { qd[CNT - 1] = FINF; qi[CNT - 1] = 0x7fffffff; }
  }
  __syncthreads();
  // rank merge of the WAVES sorted 21-lists
  if (lane < 21) {
    float d0 = wd[w][lane]; int i0 = wi[w][lane];
    int rank = lane;
#pragma unroll
    for (int w2 = 0; w2 < WAVES; w2++) {
      if (w2 == w) continue;
      for (int p = 0; p < 21; p++) {
        float ld = wd[w2][p]; int li = wi[w2][p];
        rank += (ld < d0 || (ld == d0 && li < i0)) ? 1 : 0;
      }
    }
    if (rank >= 1 && rank <= 20) idx20[(size_t)row * 20 + (rank - 1)] = i0;
    if (rank >= 1 && rank <= 4)  idx4[(size_t)row * 4 + (rank - 1)] = i0;
  }
}

// =================== KNN (N=1024): ONE wave/row, direct rank output ==========
template <int CNT>
__global__ __launch_bounds__(64) void knn_1w_lex_kernel(const float* __restrict__ verts, int N,
                                                        int* __restrict__ idx20,
                                                        int* __restrict__ idx4) {
  int row = blockIdx.x; int b = row / N, i = row - b * N;
  int lane = threadIdx.x;
  const float* vb = verts + (size_t)b * N * 3;
  float xi = vb[i * 3], yi = vb[i * 3 + 1], zi = vb[i * 3 + 2];
  float sqi = (xi * xi + yi * yi) + zi * zi;

  float qd[CNT]; int qi[CNT];
#pragma unroll
  for (int m = 0; m < CNT; m++) {
    int j = lane + m * 64;
    float xj = vb[j * 3], yj = vb[j * 3 + 1], zj = vb[j * 3 + 2];
    float sqj = (xj * xj + yj * yj) + zj * zj;
    float dot = (xi * xj + yi * yj) + zi * zj;
    qd[m] = sqi + sqj - 2.f * dot;
    qi[m] = j;
  }
#pragma unroll
  for (int k = 2; k <= CNT; k <<= 1)
#pragma unroll
    for (int j = k >> 1; j > 0; j >>= 1)
#pragma unroll
      for (int m = 0; m < CNT; m++) {
        int l = m ^ j;
        if (l > m) {
          bool up = ((m & k) == 0);
          bool sw = up ? (qd[m] > qd[l]) : (qd[m] < qd[l]);
          float td = sw ? qd[l] : qd[m]; qd[l] = sw ? qd[m] : qd[l]; qd[m] = td;
          int ti = sw ? qi[l] : qi[m]; qi[l] = sw ? qi[m] : qi[l]; qi[m] = ti;
        }
      }
  for (int r = 0; r < 21; r++) {
    float M; int widx;
    wave_argmin2(qd[0], qi[0], &M, &widx);
    if (lane == 0 && r >= 1) {
      idx20[(size_t)row * 20 + (r - 1)] = widx;
      if (r <= 4) idx4[(size_t)row * 4 + (r - 1)] = widx;
    }
    bool win = (qi[0] == widx);
#pragma unroll
    for (int m = 0; m < CNT - 1; m++) {
      qd[m] = win ? qd[m + 1] : qd[m];
      qi[m] = win ? qi[m + 1] : qi[m];
    }
    if (win) { qd[CNT - 1] = FINF; qi[CNT - 1] = 0x7fffffff; }
  }
}

// =================== conv_surface + LN + relu -> fm0 (C=32) ===================
__global__ void conv_surface_kernel(const float* __restrict__ verts,
                                    const int* __restrict__ idx20,
                                    const float* __restrict__ d0,
                                    const float* __restrict__ g, const float* __restrict__ be,
                                    float* __restrict__ out, int N) {
  int row = blockIdx.x; int b = row / N, i = row - b * N;
  int t = threadIdx.x;
  __shared__ float nd[20][3];
  const float* vb = verts + (size_t)b * N * 3;
  if (t < 20) {
    int j = idx20[(size_t)row * 20 + t];
    float dx = vb[j * 3] - vb[i * 3], dy = vb[j * 3 + 1] - vb[i * 3 + 1], dz = vb[j * 3 + 2] - vb[i * 3 + 2];
    float n2 = sqrtf(dx * dx + dy * dy + dz * dz); n2 = fmaxf(n2, 1e-12f);
    nd[t][0] = dx / n2; nd[t][1] = dy / n2; nd[t][2] = dz / n2;
  }
  __syncthreads();
  float x = 0.f;
  if (t < 32) {
    float a = d0[t], bb2 = d0[32 + t], c = d0[64 + t];
    float nrm = fmaxf(sqrtf(a * a + bb2 * bb2 + c * c), 1e-12f);
    a /= nrm; bb2 /= nrm; c /= nrm;
    float mx = -FINF;
    for (int kk = 0; kk < 20; kk++) {
      float th = fmaxf(nd[kk][0] * a + nd[kk][1] * bb2 + nd[kk][2] * c, 0.f);
      mx = fmaxf(mx, th);
    }
    x = mx;
  }
  float s = x;
  for (int off = 32; off; off >>= 1) s += __shfl_xor(s, off);
  float mean = s / 32.f;
  float dev = (t < 32) ? x - mean : 0.f;
  float s2 = dev * dev;
  for (int off = 32; off; off >>= 1) s2 += __shfl_xor(s2, off);
  float var = s2 / 32.f;
  if (t < 32) {
    float y = (x - mean) / sqrtf(var + 1e-6f) * g[t] + be[t];
    out[(size_t)row * 32 + t] = fmaxf(y, 0.f);
  }
}

// =================== GEMM: y = x(R,I) @ W(I,O) + bias (xs transposed) =========
__global__ void gemm_io_kernel(const float* __restrict__ x, const float* __restrict__ W,
                               const float* __restrict__ bias, float* __restrict__ y,
                               int R, int I, int O) {
  int rb = blockIdx.x * 8;
  int o = blockIdx.y * blockDim.x + threadIdx.x;
  __shared__ float xs[256][8];  // [k][u] -> broadcast float4 reads
  for (int u = 0; u < 8; u++)
    for (int i2 = threadIdx.x; i2 < I; i2 += blockDim.x) xs[i2][u] = x[(size_t)(rb + u) * I + i2];
  __syncthreads();
  float a[8] = {0, 0, 0, 0, 0, 0, 0, 0};
  for (int k2 = 0; k2 < I; k2++) {
    float wv = W[(size_t)k2 * O + o];
    float4 xa = *(const float4*)&xs[k2][0];
    float4 xb = *(const float4*)&xs[k2][4];
    a[0] += xa.x * wv; a[1] += xa.y * wv; a[2] += xa.z * wv; a[3] += xa.w * wv;
    a[4] += xb.x * wv; a[5] += xb.y * wv; a[6] += xb.z * wv; a[7] += xb.w * wv;
  }
  float bv = bias[o];
#pragma unroll
  for (int u = 0; u < 8; u++) y[(size_t)(rb + u) * O + o] = a[u] + bv;
}

// =================== conv_layer combine (k-loop hoisted) ===================
template <int CPT>
__global__ void combine_kernel(const float* __restrict__ verts, const int* __restrict__ idx20,
                               const float* __restrict__ fo, const float* __restrict__ dirs,
                               const float* __restrict__ g, const float* __restrict__ be,
                               float* __restrict__ out, int N, int C) {
  int row = blockIdx.x; int b = row / N, i = row - b * N;
  int t = threadIdx.x, bs = blockDim.x;
  __shared__ float nd[20][3];
  __shared__ int nidx[20];
  __shared__ float red[8];
  const float* vb = verts + (size_t)b * N * 3;
  if (t < 20) {
    int j = idx20[(size_t)row * 20 + t];
    nidx[t] = j;
    float dx = vb[j * 3] - vb[i * 3], dy = vb[j * 3 + 1] - vb[i * 3 + 1], dz = vb[j * 3 + 2] - vb[i * 3 + 2];
    float n2 = fmaxf(sqrtf(dx * dx + dy * dy + dz * dz), 1e-12f);
    nd[t][0] = dx / n2; nd[t][1] = dy / n2; nd[t][2] = dz / n2;
  }
  __syncthreads();
  const float* fob = fo + (size_t)b * N * 2 * C;
  const float* forow = fob + (size_t)i * 2 * C;
  float da[CPT], db[CPT], dc[CPT], mx[CPT];
#pragma unroll
  for (int u = 0; u < CPT; u++) {
    int c = t + u * bs;
    float a = dirs[c], bb = dirs[C + c], cc = dirs[2 * C + c];
    float nrm = fmaxf(sqrtf(a * a + bb * bb + cc * cc), 1e-12f);
    da[u] = a / nrm; db[u] = bb / nrm; dc[u] = cc / nrm;
    mx[u] = -FINF;
  }
  for (int kk = 0; kk < 20; kk++) {
    float n0 = nd[kk][0], n1 = nd[kk][1], n2v = nd[kk][2];
    const float* sup = fob + (size_t)nidx[kk] * 2 * C + C + t;
#pragma unroll
    for (int u = 0; u < CPT; u++) {
      float th = fmaxf(n0 * da[u] + n1 * db[u] + n2v * dc[u], 0.f);
      mx[u] = fmaxf(mx[u], th * sup[u * bs]);
    }
  }
  float xv[CPT];
  float ssum = 0.f;
#pragma unroll
  for (int u = 0; u < CPT; u++) {
    int c = t + u * bs;
    float val = forow[c] + mx[u];
    xv[u] = val; ssum += val;
  }
  int nw = bs >> 6;
  for (int off = 32; off; off >>= 1) ssum += __shfl_down(ssum, off);
  if ((t & 63) == 0) red[t >> 6] = ssum;
  __syncthreads();
  if (t == 0) { float s = red[0]; for (int w = 1; w < nw; w++) s += red[w]; red[0] = s; }
  __syncthreads();
  float mean = red[0] / (float)C;
  __syncthreads();
  float s2 = 0.f;
#pragma unroll
  for (int u = 0; u < CPT; u++) { float d2 = xv[u] - mean; s2 += d2 * d2; }
  for (int off = 32; off; off >>= 1) s2 += __shfl_down(s2, off);
  if ((t & 63) == 0) red[t >> 6] = s2;
  __syncthreads();
  if (t == 0) { float s = red[0]; for (int w = 1; w < nw; w++) s += red[w]; red[0] = s; }
  __syncthreads();
  float inv = 1.0f / sqrtf(red[0] / (float)C + 1e-6f);
#pragma unroll
  for (int u = 0; u < CPT; u++) {
    int c = t + u * bs;
    float yv = (xv[u] - mean) * inv * g[c] + be[c];
    out[(size_t)row * C + c] = fmaxf(yv, 0.f);
  }
}

// =================== pool (max over 4 NN) + row-select ===================
__global__ void pool_select_kernel(const float* __restrict__ fm, const int* __restrict__ idx4,
                                   const int* __restrict__ sel, const float* __restrict__ vin,
                                   float* __restrict__ vout, float* __restrict__ out,
                                   int N, int M, int C) {
  int row = blockIdx.x; int b = row / M, r = row - b * M;
  int s = sel[r];
  const int* id = idx4 + ((size_t)b * N + s) * 4;
  int i0 = id[0], i1 = id[1], i2 = id[2], i3 = id[3];
  const float* fb = fm + (size_t)b * N * C;
  for (int c = threadIdx.x; c < C; c += blockDim.x) {
    float m = fmaxf(fmaxf(fb[(size_t)i0 * C + c], fb[(size_t)i1 * C + c]),
                    fmaxf(fb[(size_t)i2 * C + c], fb[(size_t)i3 * C + c]));
    out[((size_t)b * M + r) * C + c] = m;
  }
  if (vout != nullptr && threadIdx.x < 3)
    vout[((size_t)b * M + r) * 3 + threadIdx.x] = vin[((size_t)b * N + s) * 3 + threadIdx.x];
}

// =================== token transpose ===================
__global__ void tok_kernel(const float* __restrict__ token, float* __restrict__ tok) {
  int id = blockIdx.x * 256 + threadIdx.x;
  int e = id & 63; int n = (id >> 6) & 1023;
  tok[id] = token[e * 1024 + n];
}

// =================== linear: y = x(R,I) @ W(O,I)^T + bias (+res) ===================
__global__ void linear_oi_kernel(const float* __restrict__ x, const float* __restrict__ W,
                                 const float* __restrict__ bias, const float* __restrict__ res,
                                 float* __restrict__ y, int R, int I, int O) {
  int rb = blockIdx.x * 8;
  int o = threadIdx.x;
  __shared__ float xs[8][256];
  for (int u = 0; u < 8; u++)
    for (int i2 = threadIdx.x; i2 < I; i2 += O) xs[u][i2] = x[(size_t)(rb + u) * I + i2];
  __syncthreads();
  float a[8] = {0, 0, 0, 0, 0, 0, 0, 0};
  const float* w = W + (size_t)o * I;
  for (int k2 = 0; k2 < I; k2++) {
    float wv = w[k2];
#pragma unroll
    for (int u = 0; u < 8; u++) a[u] += xs[u][k2] * wv;
  }
  float bv = bias[o];
#pragma unroll
  for (int u = 0; u < 8; u++) {
    float val = a[u] + bv;
    if (res) val += res[(size_t)(rb + u) * O + o];
    y[(size_t)(rb + u) * O + o] = val;
  }
}

// =================== tiled flash attention ===================
template <int HD, int QPT, int KS>
__global__ __launch_bounds__(256) void attn_tiled(
    const float* __restrict__ q, const float* __restrict__ kk,
    const float* __restrict__ vv, float* __restrict__ o,
    int Lq, int Lk, int H, float scale) {
  constexpr int TK = 64;
  constexpr int QG = 256 / (2 * KS);
  constexpr int QPB = QG * QPT;
  constexpr int V4 = HD / 4;
  constexpr int STR = V4 + 1;
  constexpr int HH = HD / 2;
  constexpr int V4H = HH / 4;

  __shared__ float4 Ks[TK * STR];
  __shared__ float4 Vs[TK * STR];

  int t = threadIdx.x;
  int dh = t & 1;
  int ki = (t >> 1) & (KS - 1);
  int qg = t / (2 * KS);
  int nqt = Lq / QPB;
  int qt = blockIdx.x % nqt, bh = blockIdx.x / nqt;
  int h = bh % H, b = bh / H;
  int E = H * HD;
  int q0 = qt * QPB + qg * QPT;

  const float* qbase = q + ((size_t)b * Lq + q0) * E + h * HD + dh * HH;
  const float* kbase = kk + (size_t)b * Lk * E + h * HD;
  const float* vbase = vv + (size_t)b * Lk * E + h * HD;

  float qr[QPT][HH], O[QPT][HH], m[QPT], l[QPT];
#pragma unroll
  for (int r = 0; r < QPT; r++) {
    m[r] = -FINF; l[r] = 0.f;
#pragma unroll
    for (int d = 0; d < HH; d++) { qr[r][d] = qbase[(size_t)r * E + d]; O[r][d] = 0.f; }
  }

  for (int k0 = 0; k0 < Lk; k0 += TK) {
    __syncthreads();
    for (int e = t; e < TK * V4; e += 256) {
      int rr = e / V4, cc = e - rr * V4;
      Ks[rr * STR + cc] = *(const float4*)(kbase + (size_t)(k0 + rr) * E + cc * 4);
      Vs[rr * STR + cc] = *(const float4*)(vbase + (size_t)(k0 + rr) * E + cc * 4);
    }
    __syncthreads();
#pragma unroll 1
    for (int g = 0; g < TK / KS; g += 4) {
      float sc[QPT][4];
#pragma unroll
      for (int jj = 0; jj < 4; jj++) {
        int kl = (g + jj) * KS + ki;
        float sh[QPT];
#pragma unroll
        for (int r = 0; r < QPT; r++) sh[r] = 0.f;
        const float4* kr = &Ks[kl * STR + dh * V4H];
#pragma unroll
        for (int c = 0; c < V4H; c++) {
          float4 kv = kr[c];
#pragma unroll
          for (int r = 0; r < QPT; r++)
            sh[r] += qr[r][4 * c] * kv.x + qr[r][4 * c + 1] * kv.y
                   + qr[r][4 * c + 2] * kv.z + qr[r][4 * c + 3] * kv.w;
        }
#pragma unroll
        for (int r = 0; r < QPT; r++)
          sc[r][jj] = (sh[r] + __shfl_xor(sh[r], 1)) * scale;
      }
#pragma unroll
      for (int r = 0; r < QPT; r++) {
        float tm = fmaxf(fmaxf(sc[r][0], sc[r][1]), fmaxf(sc[r][2], sc[r][3]));
        float nm = fmaxf(m[r], tm);
        float a = __expf(m[r] - nm);
        m[r] = nm;
        float ls = l[r] * a;
#pragma unroll
        for (int d = 0; d < HH; d++) O[r][d] *= a;
#pragma unroll
        for (int jj = 0; jj < 4; jj++) { sc[r][jj] = __expf(sc[r][jj] - nm); ls += sc[r][jj]; }
        l[r] = ls;
      }
#pragma unroll
      for (int jj = 0; jj < 4; jj++) {
        int kl = (g + jj) * KS + ki;
        const float4* vr = &Vs[kl * STR + dh * V4H];
#pragma unroll
        for (int c = 0; c < V4H; c++) {
          float4 v4 = vr[c];
#pragma unroll
          for (int r = 0; r < QPT; r++) {
            O[r][4 * c]     += sc[r][jj] * v4.x;
            O[r][4 * c + 1] += sc[r][jj] * v4.y;
            O[r][4 * c + 2] += sc[r][jj] * v4.z;
            O[r][4 * c + 3] += sc[r][jj] * v4.w;
          }
        }
      }
    }
  }
#pragma unroll
  for (int r = 0; r < QPT; r++) {
    float M = m[r];
#pragma unroll
    for (int mask = 2; mask < 2 * KS; mask <<= 1) M = fmaxf(M, __shfl_xor(M, mask));
    float w = __expf(m[r] - M);
    float ll = l[r] * w;
#pragma unroll
    for (int mask = 2; mask < 2 * KS; mask <<= 1) ll += __shfl_xor(ll, mask);
    float inv = 1.f / ll;
#pragma unroll
    for (int d = 0; d < HH; d++) {
      float x = O[r][d] * w;
#pragma unroll
      for (int mask = 2; mask < 2 * KS; mask <<= 1) x += __shfl_xor(x, mask);
      O[r][d] = x * inv;
    }
  }
  if (ki == 0) {
    float* obase = o + ((size_t)b * Lq + q0) * E + h * HD + dh * HH;
#pragma unroll
    for (int r = 0; r < QPT; r++)
#pragma unroll
      for (int d = 0; d < HH; d++) obase[(size_t)r * E + d] = O[r][d];
  }
}

// =================== BN (train-mode) stats & apply ===================
__global__ void bn_stats_kernel(const float* __restrict__ x, float* __restrict__ stats,
                                int R, int C) {
  int c = blockIdx.x; int t = threadIdx.x;
  __shared__ float red[8];
  float s = 0.f;
  for (int r = t; r < R; r += blockDim.x) s += x[(size_t)r * C + c];
  for (int off = 32; off; off >>= 1) s += __shfl_down(s, off);
  if ((t & 63) == 0) red[t >> 6] = s;
  __syncthreads();
  if (t == 0) { float a = red[0]; for (int w = 1; w < (int)(blockDim.x >> 6); w++) a += red[w]; red[0] = a; }
  __syncthreads();
  float mean = red[0] / (float)R;
  __syncthreads();
  float s2 = 0.f;
  for (int r = t; r < R; r += blockDim.x) { float d = x[(size_t)r * C + c] - mean; s2 += d * d; }
  for (int off = 32; off; off >>= 1) s2 += __shfl_down(s2, off);
  if ((t & 63) == 0) red[t >> 6] = s2;
  __syncthreads();
  if (t == 0) {
    float a = red[0]; for (int w = 1; w < (int)(blockDim.x >> 6); w++) a += red[w];
    stats[c] = mean; stats[C + c] = a / (float)R;
  }
}

__global__ void bn_apply_kernel(float* __restrict__ x, const float* __restrict__ stats,
                                const float* __restrict__ g, const float* __restrict__ b2,
                                int total, int C) {
  int id = blockIdx.x * blockDim.x + threadIdx.x;
  if (id >= total) return;
  int c = id % C;
  float y = (x[id] - stats[c]) / sqrtf(stats[C + c] + 1e-5f) * g[c] + b2[c];
  x[id] = fmaxf(y, 0.f);
}

// =================== final conv1x1 (xs transposed) ===================
__global__ void final_kernel(const float* __restrict__ fmf, const float* __restrict__ W,
                             const float* __restrict__ bias, float* __restrict__ out) {
  int nb = blockIdx.x * 8;
  int o = threadIdx.x;
  __shared__ float xs[1024][8];  // [c][u]
  for (int u = 0; u < 8; u++)
    for (int c = threadIdx.x; c < 1024; c += 256) xs[c][u] = fmf[(size_t)(nb + u) * 1024 + c];
  __syncthreads();
  float acc[8] = {0, 0, 0, 0, 0, 0, 0, 0};
  const float* w = W + (size_t)o * 1024;
  for (int c = 0; c < 1024; c++) {
    float wv = w[c];
    float4 xa = *(const float4*)&xs[c][0];
    float4 xb = *(const float4*)&xs[c][4];
    acc[0] += xa.x * wv; acc[1] += xa.y * wv; acc[2] += xa.z * wv; acc[3] += xa.w * wv;
    acc[4] += xb.x * wv; acc[5] += xb.y * wv; acc[6] += xb.z * wv; acc[7] += xb.w * wv;
  }
  float bv = bias[o];
#pragma unroll
  for (int u = 0; u < 8; u++) {
    int r = nb + u; int b = r >> 10; int n = r & 1023;
    out[((size_t)(b * 256 + o) << 10) + n] = acc[u] + bv;
  }
}

// =================== launch ===================
extern "C" void kernel_launch(void* const* d_in, const int* in_sizes, int n_in,
                              void* d_out, int out_size, void* d_ws, size_t ws_size,
                              hipStream_t stream) {
  (void)in_sizes; (void)n_in; (void)out_size;
  const float* vertices = (const float*)d_in[0];
  const float* d0       = (const float*)d_in[1];
  const float* g0       = (const float*)d_in[2];
  const float* be0      = (const float*)d_in[3];
  const float* w1       = (const float*)d_in[4];
  const float* b1       = (const float*)d_in[5];
  const float* dir1     = (const float*)d_in[6];
  const float* g1       = (const float*)d_in[7];
  const float* be1      = (const float*)d_in[8];
  const float* w2       = (const float*)d_in[9];
  const float* b2       = (const float*)d_in[10];
  const float* dir2     = (const float*)d_in[11];
  const float* g2       = (const float*)d_in[12];
  const float* be2      = (const float*)d_in[13];
  const float* w3       = (const float*)d_in[14];
  const float* b3       = (const float*)d_in[15];
  const float* dir3     = (const float*)d_in[16];
  const float* g3       = (const float*)d_in[17];
  const float* be3      = (const float*)d_in[18];
  const float* token    = (const float*)d_in[19];
  const float* a1_in_w  = (const float*)d_in[20];
  const float* a1_in_b  = (const float*)d_in[21];
  const float* a1_out_w = (const float*)d_in[22];
  const float* a1_out_b = (const float*)d_in[23];
  const float* ffn1_w   = (const float*)d_in[24];
  const float* ffn1_b   = (const float*)d_in[25];
  const float* bg       = (const float*)d_in[26];
  const float* bbp      = (const float*)d_in[27];
  const float* ffn2_w   = (const float*)d_in[28];
  const float* ffn2_b   = (const float*)d_in[29];
  const float* a2_in_w  = (const float*)d_in[30];
  const float* a2_in_b  = (const float*)d_in[31];
  const float* a2_out_w = (const float*)d_in[32];
  const float* a2_out_b = (const float*)d_in[33];
  const float* w7       = (const float*)d_in[34];
  const float* b7       = (const float*)d_in[35];
  const float* dir7     = (const float*)d_in[36];
  const float* g4       = (const float*)d_in[37];
  const float* be4      = (const float*)d_in[38];
  const float* c8_w     = (const float*)d_in[39];
  const float* c8_b     = (const float*)d_in[40];
  float* out = (float*)d_out;
  float* ws = (float*)d_ws;

  if (ws_size < 78568448u) return;

  float* FO     = ws + 0;
  float* S1     = ws + 8388608;
  float* S2     = ws + 12582912;
  float* S3     = ws + 13631488;
  float* QUERY2 = ws + 14680064;
  float* CROSS  = ws + 15728640;
  float* FM1P   = ws + 16777216;
  float* FM3P   = FM1P + 262144;
  float* TOK    = FM3P + 262144;
  float* Q1     = TOK + 262144;
  float* K1     = Q1 + 262144;
  float* VA1    = K1 + 262144;
  float* ATT1   = VA1 + 262144;
  float* K2     = ATT1 + 262144;
  float* V2     = K2 + 262144;
  float* V1     = V2 + 262144;
  float* BNST   = V1 + 12288;
  int* IDX20_0  = (int*)(BNST + 512);
  int* IDX4_0   = IDX20_0 + 327680;
  int* IDX20_1  = IDX4_0 + 65536;
  int* IDX4_1   = IDX20_1 + 81920;
  int* SEL1     = IDX4_1 + 16384;
  int* SEL2     = SEL1 + 1024;

  perm_both_kernel<<<2, 1024, 0, stream>>>(SEL1, SEL2);

  knn_lex_kernel<32, 2><<<4 * 4096, 128, 0, stream>>>(vertices, 4096, IDX20_0, IDX4_0);
  conv_surface_kernel<<<4 * 4096, 64, 0, stream>>>(vertices, IDX20_0, d0, g0, be0, S2, 4096);
  gemm_io_kernel<<<dim3(2048, 1), 128, 0, stream>>>(S2, w1, b1, FO, 16384, 32, 128);
  combine_kernel<1><<<16384, 64, 0, stream>>>(vertices, IDX20_0, FO, dir1, g1, be1, S1, 4096, 64);
  pool_select_kernel<<<4096, 64, 0, stream>>>(S1, IDX4_0, SEL1, vertices, V1, FM1P, 4096, 1024, 64);

  knn_1w_lex_kernel<16><<<4 * 1024, 64, 0, stream>>>(V1, 1024, IDX20_1, IDX4_1);
  gemm_io_kernel<<<dim3(512, 1), 256, 0, stream>>>(FM1P, w2, b2, FO, 4096, 64, 256);
  combine_kernel<1><<<4096, 128, 0, stream>>>(V1, IDX20_1, FO, dir2, g2, be2, S2, 1024, 128);
  gemm_io_kernel<<<dim3(512, 2), 256, 0, stream>>>(S2, w3, b3, FO, 4096, 128, 512);
  combine_kernel<1><<<4096, 256, 0, stream>>>(V1, IDX20_1, FO, dir3, g3, be3, S3, 1024, 256);
  pool_select_kernel<<<1024, 256, 0, stream>>>(S3, IDX4_1, SEL2, nullptr, nullptr, FM3P, 1024, 256, 256);

  // MHA1 (tok as Q, fm1p as KV) + residual
  tok_kernel<<<1024, 256, 0, stream>>>(token, TOK);
  linear_oi_kernel<<<512, 64, 0, stream>>>(TOK, a1_in_w, a1_in_b, nullptr, Q1, 4096, 64, 64);
  linear_oi_kernel<<<512, 64, 0, stream>>>(FM1P, a1_in_w + 64 * 64, a1_in_b + 64, nullptr, K1, 4096, 64, 64);
  linear_oi_kernel<<<512, 64, 0, stream>>>(FM1P, a1_in_w + 128 * 64, a1_in_b + 128, nullptr, VA1, 4096, 64, 64);
  attn_tiled<16, 4, 8><<<256, 256, 0, stream>>>(Q1, K1, VA1, ATT1, 1024, 1024, 4, 0.25f);
  linear_oi_kernel<<<512, 64, 0, stream>>>(ATT1, a1_out_w, a1_out_b, FM1P, S3, 4096, 64, 64);

  // FFN
  linear_oi_kernel<<<512, 256, 0, stream>>>(S3, ffn1_w, ffn1_b, nullptr, S2, 4096, 64, 256);
  bn_stats_kernel<<<256, 256, 0, stream>>>(S2, BNST, 4096, 256);
  bn_apply_kernel<<<4096, 256, 0, stream>>>(S2, BNST, bg, bbp, 4096 * 256, 256);
  linear_oi_kernel<<<512, 256, 0, stream>>>(S2, ffn2_w, ffn2_b, nullptr, QUERY2, 4096, 256, 256);

  // MHA2 (query2 as Q, fm3p as KV) + residual
  linear_oi_kernel<<<512, 256, 0, stream>>>(QUERY2, a2_in_w, a2_in_b, nullptr, S3, 4096, 256, 256);
  linear_oi_kernel<<<128, 256, 0, stream>>>(FM3P, a2_in_w + 256 * 256, a2_in_b + 256, nullptr, K2, 1024, 256, 256);
  linear_oi_kernel<<<128, 256, 0, stream>>>(FM3P, a2_in_w + 512 * 256, a2_in_b + 512, nullptr, V2, 1024, 256, 256);
  attn_tiled<64, 2, 8><<<512, 256, 0, stream>>>(S3, K2, V2, S1, 1024, 256, 4, 0.125f);
  linear_oi_kernel<<<512, 256, 0, stream>>>(S1, a2_out_w, a2_out_b, QUERY2, CROSS, 4096, 256, 256);

  // conv_layer7 + final conv1x1
  gemm_io_kernel<<<dim3(512, 8), 256, 0, stream>>>(CROSS, w7, b7, FO, 4096, 256, 2048);
  combine_kernel<4><<<4096, 256, 0, stream>>>(V1, IDX20_1, FO, dir7, g4, be4, S1, 1024, 1024);
  final_kernel<<<512, 256, 0, stream>>>(S1, c8_w, c8_b, out);
}